// Round 14
// baseline (397.059 us; speedup 1.0000x reference)
//
#include <hip/hip_runtime.h>
#include <math.h>

#define PI_F 3.14159265358979323846f

typedef __bf16 bf16x8 __attribute__((ext_vector_type(8)));
typedef float floatx4 __attribute__((ext_vector_type(4)));
union U8 { unsigned short u[8]; uint4 q; bf16x8 v; };

// sigmoid-form GELU: v * sigmoid(1.702 v)
__device__ __forceinline__ float gelu_sig(float v) {
    float e = __builtin_amdgcn_exp2f(-2.4554670f * v);   // exp(-1.702 v)
    return v * __builtin_amdgcn_rcpf(1.0f + e);
}
__device__ __forceinline__ int rfl(int x) { return __builtin_amdgcn_readfirstlane(x); }

__device__ __forceinline__ unsigned short f2bf(float f) {   // RNE fp32->bf16
    unsigned int u = __float_as_uint(f);
    u += 0x7fffu + ((u >> 16) & 1u);
    return (unsigned short)(u >> 16);
}
__device__ __forceinline__ float bf2f(unsigned short h) {
    return __uint_as_float(((unsigned int)h) << 16);
}

// ---------------- emb ----------------
__global__ void k_emb(const float* __restrict__ time_i, const float* __restrict__ conditions,
                      const float* __restrict__ t_embed_w, const float* __restrict__ t_embed_b,
                      const float* __restrict__ c_embed_w, const float* __restrict__ c_embed_b,
                      const float* __restrict__ lift_b, float* __restrict__ embk) {
    __shared__ float red[8][32];
    int t = threadIdx.x;
    int b = blockIdx.x;
    int c = t & 31, lg = t >> 5;
    float acc = 0.0f;
    if (lg == 0) {
        acc = t_embed_b[c] + c_embed_b[c] + lift_b[c];
        float tv = time_i[b];
        float ang = PI_F * tv;
        const float* tw = t_embed_w + c * 11;
        for (int i = 0; i < 5; i++) {
            float s, co; sincosf(ang, &s, &co);
            acc += co * tw[i] + s * tw[5 + i];
            ang *= 2.0f;
        }
        acc += tv * tw[10];
    }
    const float* cw = c_embed_w + c * 352;
    for (int j = 0; j < 4; j++) {
        int l = lg * 4 + j;
        float v = conditions[b * 32 + l];
        float ang = PI_F * v;
        for (int i = 0; i < 5; i++) {
            float s, co; sincosf(ang, &s, &co);
            acc += co * cw[l * 10 + i] + s * cw[l * 10 + 5 + i];
            ang *= 2.0f;
        }
        acc += v * cw[320 + l];
    }
    red[lg][c] = acc;
    __syncthreads();
    if (t < 32) {
        float s = 0.0f;
        for (int g = 0; g < 8; g++) s += red[g][t];
        embk[b * 32 + t] = s;
    }
}

// -------- k_wt: bf16 constants + fp32 uniform-twiddle table Tp1g --------
__global__ void k_wt(const float* __restrict__ byp_w, const float* __restrict__ lift_w,
                     unsigned short* __restrict__ wbh, unsigned short* __restrict__ wlbf,
                     unsigned short* __restrict__ Tinv, unsigned short* __restrict__ TfT,
                     float* __restrict__ Tp1g) {
    int idx = blockIdx.x * 256 + threadIdx.x;
    const float th = PI_F / 32.0f;
    if (idx < 4096) {
        wbh[idx] = f2bf(byp_w[idx]);          // [l][o][i] (A-fragment layout)
    } else if (idx < 6144) {
        int j = idx - 4096;                   // o*64 + q
        int o = j >> 6, q = j & 63;
        wlbf[j] = (q < 37) ? f2bf(lift_w[o * 37 + q]) : 0;
    } else if (idx < 8192) {
        int j = idx - 6144;                   // nz*32 + k
        int nz = j >> 5, k = j & 31;
        int kz = k >> 1;
        float val = 0.0f;
        if (kz < 8) {
            float a = (float)((kz * nz) & 63) * th;
            val = (k & 1) ? sinf(a) : cosf(a);
        }
        Tinv[j] = f2bf(val);
    } else if (idx < 9216) {
        int j = idx - 8192;                   // kcol*64 + nz
        int kcol = j >> 6, nz = j & 63;
        int kz = kcol >> 1;
        float a = (float)((kz * nz) & 63) * th;
        float val = (kcol & 1) ? -sinf(a) : cosf(a);
        TfT[j] = f2bf(val);
    } else if (idx < 9728) {
        int j = idx - 9216;                   // ny*8 + ky
        int ny = j >> 3, ky = j & 7;
        float a = (float)((ky * ny) & 63) * th;
        Tp1g[j * 2] = cosf(a);
        Tp1g[j * 2 + 1] = sinf(a);
    }
}

// XCD swizzle for the 8192-grid k_lift
__device__ __forceinline__ void swz8k(int blk, int& b, int& nx, int& ny) {
    int x = blk & 7;
    int j = blk >> 3;
    int pair = x * 16 + (j >> 6);
    ny = j & 63;
    b = pair >> 6;
    nx = pair & 63;
}

// ------- k_lift: MFMA lift conv + emb + MFMA forward z-DFT. x0 in bf16. -------
__global__ __launch_bounds__(256) void k_lift(const float* __restrict__ state_in,
        const float* __restrict__ node_pos, const unsigned short* __restrict__ wlbf,
        const float* __restrict__ embk, const unsigned short* __restrict__ TfT,
        unsigned short* __restrict__ x0, float2* __restrict__ a1) {
    __shared__ __align__(16) float SL[7584];
    unsigned short* fsT  = (unsigned short*)SL;          // [nz][72] u16 (2304 f)
    unsigned short* ysbf = (unsigned short*)(SL + 2304); // [o][72] u16 (1152 f)
    float* pz   = SL + 3456;                             // 4096 f
    float* pz2  = SL + 3456 + 512;                       // 512 f (linear)
    float* bias = SL + 7552;                             // 32
    int t = threadIdx.x;
    int b, nx, ny; swz8k(blockIdx.x, b, nx, ny);
    int nxy = nx * 64 + ny;

    if (t < 32) bias[t] = embk[b * 32 + t];
    {
        for (int u = t; u < 2048; u += 256) {
            int row = u >> 5, col = 37 + (u & 31);
            fsT[row * 72 + col] = 0;
        }
    }
    if (t < 192) {
        int nzf = t / 3;
        int l = t - nzf * 3;
        float p = node_pos[((size_t)b * 262144 + (nxy << 6)) * 3 + t];
        float s, c; sincosf(PI_F * p, &s, &c);
        unsigned short* row = fsT + nzf * 72;
        #pragma unroll
        for (int i = 0; i < 5; i++) {
            row[4 + l * 10 + i] = f2bf(c);
            row[4 + l * 10 + 5 + i] = f2bf(s);
            float nc = 2.0f * c * c - 1.0f;
            s = 2.0f * s * c;
            c = nc;
        }
        row[34 + l] = f2bf(p);
    } else {
        int nzf = t - 192;
        const float4 s4 = *(const float4*)(state_in + ((size_t)b * 262144 + (nxy << 6) + nzf) * 4);
        unsigned short* row = fsT + nzf * 72;
        row[0] = f2bf(s4.x); row[1] = f2bf(s4.y);
        row[2] = f2bf(s4.z); row[3] = f2bf(s4.w);
    }
    __syncthreads();

    int lane = t & 63;
    int w = rfl(t >> 6);
    int otile = w & 1;
    int nzt0 = (w >> 1) * 2;
    int l15 = lane & 15;
    int quad = lane >> 4;

    U8 a0, a1_;
    a0.q = *(const uint4*)(wlbf + ((otile * 16 + l15) << 6) + (quad << 3));
    a1_.q = *(const uint4*)(wlbf + ((otile * 16 + l15) << 6) + 32 + (quad << 3));
    floatx4 cb;
    #pragma unroll
    for (int r = 0; r < 4; r++) cb[r] = bias[otile * 16 + quad * 4 + r];
    floatx4 dz = {0.0f, 0.0f, 0.0f, 0.0f};

    #pragma unroll
    for (int m = 0; m < 2; m++) {
        int nzc = (nzt0 + m) * 16 + l15;
        U8 b0, b1_;
        b0.q = *(const uint4*)(fsT + nzc * 72 + (quad << 3));
        b1_.q = *(const uint4*)(fsT + nzc * 72 + 32 + (quad << 3));
        floatx4 d = __builtin_amdgcn_mfma_f32_16x16x32_bf16(a0.v, b0.v, cb, 0, 0, 0);
        d = __builtin_amdgcn_mfma_f32_16x16x32_bf16(a1_.v, b1_.v, d, 0, 0, 0);
        #pragma unroll
        for (int r = 0; r < 4; r++) {
            int o = otile * 16 + quad * 4 + r;
            ysbf[o * 72 + nzc] = f2bf(d[r]);
        }
    }
    __syncthreads();
    {   // coalesced x0 write
        int ch = t >> 3, q = t & 7;
        uint4 v = *(const uint4*)(ysbf + ch * 72 + q * 8);
        *(uint4*)(x0 + (((size_t)(b * 32 + ch)) << 18) + (nxy << 6) + q * 8) = v;
    }
    {   // forward z-DFT via MFMA: wave (otile, khalf)
        int khalf = w >> 1;
        U8 ay, bt;
        ay.q = *(const uint4*)(ysbf + (otile * 16 + l15) * 72 + khalf * 32 + (quad << 3));
        bt.q = *(const uint4*)(TfT + (l15 << 6) + khalf * 32 + (quad << 3));
        floatx4 d = __builtin_amdgcn_mfma_f32_16x16x32_bf16(ay.v, bt.v, dz, 0, 0, 0);
        *(floatx4*)(pz + w * 1024 + lane * 4) = d;
    }
    __syncthreads();
    if (w < 2) {
        float4 p0 = *(float4*)(pz + w * 1024 + lane * 4);
        float4 p1 = *(float4*)(pz + (w + 2) * 1024 + lane * 4);
        float pv[4] = {p0.x + p1.x, p0.y + p1.y, p0.z + p1.z, p0.w + p1.w};
        #pragma unroll
        for (int r = 0; r < 4; r++)
            pz2[(otile * 16 + quad * 4 + r) * 16 + l15] = pv[r];
    }
    __syncthreads();
    if (t < 128) {
        float4 v = *(float4*)(pz2 + t * 4);
        float* a1f = (float*)a1 + ((size_t)(b * 4096 + nxy)) * 512;
        *(float4*)(a1f + t * 4) = v;
    }
}

// =================== spectral mid-section ===================

// k_p1: forward y-DFT over ny-QUARTERS with uniform-twiddle s_loads. 512 blocks.
__global__ __launch_bounds__(256) void k_p1(const float2* __restrict__ a1,
        const float2* __restrict__ Tp1g, float2* __restrict__ a2p) {
    int blk = blockIdx.x, t = threadIdx.x;
    int x = blk & 7, r = blk >> 3;        // r 0..63
    int pair = x * 16 + (r & 15);
    int qtr = r >> 4;                     // 0..3
    const float2* src = a1 + ((size_t)(pair * 64 + qtr * 16)) * 256 + t;
    float accr[8], acci[8];
    #pragma unroll
    for (int k = 0; k < 8; k++) { accr[k] = 0.0f; acci[k] = 0.0f; }
    #pragma unroll 4
    for (int j = 0; j < 16; j++) {
        int ny = qtr * 16 + j;
        float2 v = src[(size_t)j * 256];
        const float2* tw = Tp1g + ny * 8;    // block-uniform -> s_load
        #pragma unroll
        for (int ky = 0; ky < 8; ky++) {
            float2 w2 = tw[ky];
            accr[ky] += v.x * w2.x + v.y * w2.y;   // e^{-i ky ny θ}
            acci[ky] += v.y * w2.x - v.x * w2.y;
        }
    }
    float4* dst = (float4*)(a2p + (size_t)qtr * 262144 + ((size_t)(pair * 256 + t)) * 8);
    #pragma unroll
    for (int j = 0; j < 4; j++)
        dst[j] = make_float4(accr[2 * j], acci[2 * j], accr[2 * j + 1], acci[2 * j + 1]);
}

// k_p2: forward x-DFT (sums 4 quarter-partials)
__global__ __launch_bounds__(256) void k_p2(const float2* __restrict__ a2p,
                                            float2* __restrict__ xft) {
    __shared__ __align__(16) float2 SH[1040];
    int blk = blockIdx.x, t = threadIdx.x;
    for (int lu = 0; lu < 2; lu++) {
        int un = blk * 2 + lu;
        int b = un >> 8, ckz = un & 255;
        size_t base = (size_t)b * 131072 + (size_t)ckz * 8;
        for (int e = t; e < 512; e += 256) {
            size_t a = base + (size_t)(e >> 3) * 2048 + (e & 7);
            float2 v0 = a2p[a];
            float2 v1 = a2p[a + 262144];
            float2 v2 = a2p[a + 524288];
            float2 v3 = a2p[a + 786432];
            SH[lu * 520 + e] = make_float2(v0.x + v1.x + v2.x + v3.x,
                                           v0.y + v1.y + v2.y + v3.y);
        }
    }
    __syncthreads();
    if (t < 128) {
        int lu = t >> 6, out = t & 63;
        int un = blk * 2 + lu;
        int kx = out & 7;
        float sn, cc; sincosf((float)kx * (PI_F / 32.0f), &sn, &cc);
        float bsn = -sn;
        float tc = 1.0f, ts = 0.0f, rr = 0.0f, ri = 0.0f;
        const float2* row = SH + lu * 520 + (out >> 3);
        for (int nx = 0; nx < 64; nx++) {
            float2 v = row[nx * 8];
            rr += v.x * tc - v.y * ts;
            ri += v.x * ts + v.y * tc;
            float nt = tc * cc - ts * bsn; ts = ts * cc + tc * bsn; tc = nt;
        }
        xft[(size_t)un * 64 + out] = make_float2(rr, ri);
    }
}

// k_p3: mode mix over i-QUARTERS. 512 blocks.
__global__ __launch_bounds__(256) void k_p3(const float2* __restrict__ xft,
        const float* __restrict__ wr, const float* __restrict__ wi,
        float2* __restrict__ yftp) {
    __shared__ __align__(16) float2 SH[64];
    int blk = blockIdx.x, t = threadIdx.x;
    int unit = blk >> 2, iq = blk & 3;
    int b = unit >> 6, kx = (unit >> 3) & 7, ky = unit & 7;
    if (t < 64) {
        int il = t >> 3, kz = t & 7;
        int i = iq * 8 + il;
        SH[t] = xft[((size_t)((b * 32 + i) * 8 + kz)) * 64 + ky * 8 + kx];
    }
    __syncthreads();
    int o = t >> 3, kz = t & 7;
    float yr = 0.0f, yi = 0.0f;
    for (int il = 0; il < 8; il++) {
        int i = iq * 8 + il;
        float2 xv = SH[il * 8 + kz];
        int wofs = ((i * 32 + o) << 9) + kx * 64 + ky * 8 + kz;
        float wrv = wr[wofs], wiv = wi[wofs];
        yr += xv.x * wrv - xv.y * wiv;
        yi += xv.x * wiv + xv.y * wrv;
    }
    yftp[(size_t)iq * 32768 + ((size_t)((b * 32 + o) * 8 + kz)) * 64 + ky * 8 + kx]
        = make_float2(yr, yi);
}

// k_p4: inverse x (sums 4 quarter-partials) -> b1[b][nx][o*8+kz][ky]
__global__ __launch_bounds__(256) void k_p4(const float2* __restrict__ yftp,
                                            float2* __restrict__ b1) {
    __shared__ __align__(16) float2 SH[4608];
    int blk = blockIdx.x, t = threadIdx.x;
    for (int u = 0; u < 2; u++) {
        if (u) __syncthreads();
        int unit = blk * 2 + u;
        int b = unit >> 8, nx = (unit >> 2) & 63, og = unit & 3;
        size_t sbase = ((size_t)(b * 32 + og * 8)) * 512;
        for (int e = t; e < 4096; e += 256) {
            float2 v0 = yftp[sbase + e];
            float2 v1 = yftp[32768 + sbase + e];
            float2 v2 = yftp[65536 + sbase + e];
            float2 v3 = yftp[98304 + sbase + e];
            SH[(e >> 3) * 9 + (e & 7)] = make_float2(v0.x + v1.x + v2.x + v3.x,
                                                     v0.y + v1.y + v2.y + v3.y);
        }
        __syncthreads();
        float cs, ss; sincosf((float)nx * (PI_F / 32.0f), &ss, &cs);
        float2* dst = b1 + ((size_t)(b * 64 + nx)) * 2048 + og * 512;
        for (int h = 0; h < 2; h++) {
            int idx = h * 256 + t;
            const float2* row = SH + idx * 9;
            float c = 1.0f, s = 0.0f, rr = 0.0f, ri = 0.0f;
            #pragma unroll
            for (int kx = 0; kx < 8; kx++) {
                float2 y = row[kx];
                rr += y.x * c - y.y * s;
                ri += y.x * s + y.y * c;
                float nc = c * cs - s * ss; s = s * cs + c * ss; c = nc;
            }
            dst[idx] = make_float2(rr, ri);
        }
    }
}

// ------- k_fin (batch-2 ny columns): inverse-y (reg-cached b1, s_load twiddles)
//         + chained MFMA (bypass + inverse-z) + gelu
//         + (l<3) in-wave chained MFMA fwd z-DFT  OR  (l==3) fused proj+residual -------
__global__ __launch_bounds__(256) void k_fin(
        const unsigned short* __restrict__ xin, const float2* __restrict__ b1,
        const unsigned short* __restrict__ wbh, const float* __restrict__ bb,
        const unsigned short* __restrict__ Tinv, const unsigned short* __restrict__ TfT,
        const float2* __restrict__ Tp1g, unsigned short* __restrict__ xout,
        float2* __restrict__ a1, int do_z, int do_proj,
        const float* __restrict__ state_in, const float* __restrict__ p1w,
        const float* __restrict__ p1b, const float* __restrict__ p2w,
        const float* __restrict__ p2b, float* __restrict__ outp) {
    __shared__ __align__(16) float S[9952];
    float* b1sr = S;                              // 2112 (dead after inverse-y)
    float* b1si = S + 2112;                       // 2112 -> 4224
    float* pz2  = S;                              // 1024 alias (fwd-z, 2 cols)
    float* pr   = S;                              // 1024 alias (proj partials)
    unsigned short* xsu  = (unsigned short*)(S + 4224);  // [col][ch][66] u16, 1056 f/col
    unsigned short* msbf = (unsigned short*)(S + 6336);  // [col][o][40] u16, 640 f/col
    unsigned short* ysbf = (unsigned short*)(S + 7616);  // [col][o][72] u16, 1152 f/col
    float* bias = S + 9920;                       // 32
    int t = threadIdx.x;

    int xx = blockIdx.x & 7;
    int jj = blockIdx.x >> 3;             // 0..511
    int pair = xx * 16 + (jj & 15);       // 0..127, XCD-local per (b,nx)
    int nyp = jj >> 4;                    // 0..31
    int b = pair >> 6, nx = pair & 63;
    int nxy0 = nx * 64 + nyp * 2;

    if (t < 32) bias[t] = bb[t];
    for (int u = t; u < 1280; u += 256) ((unsigned int*)msbf)[u] = 0;   // zero all msbf
    {   // stage xin both cols
        int ch = t >> 3, q = t & 7;
        #pragma unroll
        for (int c = 0; c < 2; c++) {
            uint4 v = *(const uint4*)(xin + (((size_t)b) << 23) + ((size_t)(nxy0 + c) << 6)
                                      + ((size_t)ch << 18) + q * 8);
            unsigned int* dst = (unsigned int*)(xsu + c * 2112 + ch * 66 + q * 8);
            dst[0] = v.x; dst[1] = v.y; dst[2] = v.z; dst[3] = v.w;
        }
    }
    const float2* bsrc = b1 + ((size_t)(b * 64 + nx)) * 2048;   // shared by both cols
    for (int u = 0; u < 8; u++) {
        int g = u * 256 + t;
        float2 v = bsrc[g];
        int ky = g & 7, okz = g >> 3;
        b1sr[ky * 264 + okz] = v.x;
        b1si[ky * 264 + okz] = v.y;
    }
    __syncthreads();

    const float scale = 1.0f / 262144.0f;
    {   // inverse-y for both cols from register-cached b1 + s_load twiddles
        float vr[8], vi[8];
        #pragma unroll
        for (int ky = 0; ky < 8; ky++) {
            vr[ky] = b1sr[ky * 264 + t];
            vi[ky] = b1si[ky * 264 + t];
        }
        int kz = t & 7;
        float sc = (kz == 0) ? scale : 2.0f * scale;
        #pragma unroll
        for (int c = 0; c < 2; c++) {
            int ny = nyp * 2 + c;
            const float2* tw = Tp1g + ny * 8;      // block-uniform -> s_load
            float mr = 0.0f, mi = 0.0f;
            #pragma unroll
            for (int ky = 0; ky < 8; ky++) {
                float2 w2 = tw[ky];
                mr += vr[ky] * w2.x - vi[ky] * w2.y;   // e^{+i ky ny θ}
                mi += vr[ky] * w2.y + vi[ky] * w2.x;
            }
            unsigned int pk = (unsigned int)f2bf(mr * sc)
                            | ((unsigned int)f2bf(-mi * sc) << 16);
            ((unsigned int*)msbf)[c * 640 + (t >> 3) * 20 + kz] = pk;
        }
    }
    __syncthreads();

    // ---- chained MFMA per wave (otile, col): 4 nz-tiles each ----
    int lane = t & 63;
    int w = rfl(t >> 6);
    int otile = w & 1, col = w >> 1;
    int l15 = lane & 15, quad = lane >> 4;

    U8 aw, ams;
    aw.q = *(const uint4*)(wbh + ((otile * 16 + l15) << 5) + (quad << 3));
    ams.q = *(const uint4*)(msbf + col * 1280 + (otile * 16 + l15) * 40 + (quad << 3));
    floatx4 cb;
    #pragma unroll
    for (int r = 0; r < 4; r++) cb[r] = bias[otile * 16 + quad * 4 + r];

    const unsigned short* xs_c = xsu + col * 2112;
    unsigned short* ys_c = ysbf + col * 2304;
    #pragma unroll
    for (int m = 0; m < 4; m++) {
        int nzc = m * 16 + l15;
        U8 bx, bt;
        #pragma unroll
        for (int j = 0; j < 8; j++) bx.u[j] = xs_c[(quad * 8 + j) * 66 + nzc];
        bt.q = *(const uint4*)(Tinv + (nzc << 5) + (quad << 3));   // global, L1-broadcast
        floatx4 d = __builtin_amdgcn_mfma_f32_16x16x32_bf16(aw.v, bx.v, cb, 0, 0, 0);
        d = __builtin_amdgcn_mfma_f32_16x16x32_bf16(ams.v, bt.v, d, 0, 0, 0);
        #pragma unroll
        for (int r = 0; r < 4; r++) {
            int o = otile * 16 + quad * 4 + r;
            ys_c[o * 72 + nzc] = f2bf(gelu_sig(d[r]));
        }
    }
    __syncthreads();

    size_t colbase0 = (((size_t)b) << 23) + ((size_t)nxy0 << 6);
    if (!do_proj) {   // coalesced xout: one uint4 per thread per col
        int ch = t >> 3, q = t & 7;
        #pragma unroll
        for (int c = 0; c < 2; c++) {
            uint4 v = *(const uint4*)(ysbf + c * 2304 + ch * 72 + q * 8);
            *(uint4*)(xout + colbase0 + ((size_t)c << 6) + ((size_t)ch << 18) + q * 8) = v;
        }
    }

    if (do_z) {   // fwd-z: wave (otile,col) chains both K-halves -> no cross-wave reduce
        U8 ay0, ay1, bt0, bt1;
        const unsigned short* yr = ysbf + col * 2304 + (otile * 16 + l15) * 72;
        ay0.q = *(const uint4*)(yr + (quad << 3));
        ay1.q = *(const uint4*)(yr + 32 + (quad << 3));
        bt0.q = *(const uint4*)(TfT + (l15 << 6) + (quad << 3));
        bt1.q = *(const uint4*)(TfT + (l15 << 6) + 32 + (quad << 3));
        floatx4 dzero = {0.0f, 0.0f, 0.0f, 0.0f};
        floatx4 d = __builtin_amdgcn_mfma_f32_16x16x32_bf16(ay0.v, bt0.v, dzero, 0, 0, 0);
        d = __builtin_amdgcn_mfma_f32_16x16x32_bf16(ay1.v, bt1.v, d, 0, 0, 0);
        #pragma unroll
        for (int r = 0; r < 4; r++)
            pz2[col * 512 + (otile * 16 + quad * 4 + r) * 16 + l15] = d[r];
        __syncthreads();
        {
            int c = t >> 7, idx = t & 127;
            float4 v = *(float4*)(pz2 + c * 512 + idx * 4);
            float* a1f = (float*)a1 + ((size_t)(b * 4096 + nxy0 + c)) * 512;
            *(float4*)(a1f + idx * 4) = v;       // coalesced 2 KB per col
        }
    }

    if (do_proj) {   // fused proj1 -> gelu -> proj2 -> residual, cols sequential
        int nz = t & 63;
        for (int c = 0; c < 2; c++) {
            if (c) __syncthreads();
            float xv[32];
            #pragma unroll
            for (int i = 0; i < 32; i++) xv[i] = bf2f(ysbf[c * 2304 + i * 72 + nz]);
            float r0 = 0.f, r1 = 0.f, r2 = 0.f, r3 = 0.f;
            #pragma unroll
            for (int k = 0; k < 8; k++) {
                int o = w * 8 + k;
                float a = p1b[o];
                const float* wr2 = p1w + o * 32;
                #pragma unroll
                for (int i = 0; i < 32; i++) a += wr2[i] * xv[i];
                float h = gelu_sig(a);
                r0 += p2w[0 * 32 + o] * h;
                r1 += p2w[1 * 32 + o] * h;
                r2 += p2w[2 * 32 + o] * h;
                r3 += p2w[3 * 32 + o] * h;
            }
            *(float4*)(pr + w * 256 + nz * 4) = make_float4(r0, r1, r2, r3);
            __syncthreads();
            if (t < 64) {
                float4 a0 = *(float4*)(pr + 0 * 256 + t * 4);
                float4 a1_ = *(float4*)(pr + 1 * 256 + t * 4);
                float4 a2 = *(float4*)(pr + 2 * 256 + t * 4);
                float4 a3 = *(float4*)(pr + 3 * 256 + t * 4);
                size_t base = ((size_t)b * 262144 + ((size_t)(nxy0 + c) << 6) + t) * 4;
                float4 sv = *(const float4*)(state_in + base);
                *(float4*)(outp + base) = make_float4(
                    sv.x + 0.05f * (p2b[0] + a0.x + a1_.x + a2.x + a3.x),
                    sv.y + 0.05f * (p2b[1] + a0.y + a1_.y + a2.y + a3.y),
                    sv.z + 0.05f * (p2b[2] + a0.z + a1_.z + a2.z + a3.z),
                    sv.w + 0.05f * (p2b[3] + a0.w + a1_.w + a2.w + a3.w));
            }
        }
    }
}

extern "C" void kernel_launch(void* const* d_in, const int* in_sizes, int n_in,
                              void* d_out, int out_size, void* d_ws, size_t ws_size,
                              hipStream_t stream) {
    const float* state_in   = (const float*)d_in[0];
    const float* node_pos   = (const float*)d_in[1];
    const float* time_i     = (const float*)d_in[3];
    const float* conditions = (const float*)d_in[4];
    const float* t_embed_w  = (const float*)d_in[5];
    const float* t_embed_b  = (const float*)d_in[6];
    const float* c_embed_w  = (const float*)d_in[7];
    const float* c_embed_b  = (const float*)d_in[8];
    const float* lift_w     = (const float*)d_in[9];
    const float* lift_b     = (const float*)d_in[10];
    const float* spec_wr    = (const float*)d_in[11];
    const float* spec_wi    = (const float*)d_in[12];
    const float* byp_w      = (const float*)d_in[13];
    const float* byp_b      = (const float*)d_in[14];
    const float* proj1_w    = (const float*)d_in[15];
    const float* proj1_b    = (const float*)d_in[16];
    const float* proj2_w    = (const float*)d_in[17];
    const float* proj2_b    = (const float*)d_in[18];
    float* out = (float*)d_out;
    float* ws  = (float*)d_ws;

    unsigned short* xA = (unsigned short*)ws;                 // 16777216 u16
    unsigned short* xB = (unsigned short*)(ws + 8388608);     // 16777216 u16
    float2* a1   = (float2*)(ws + 16777216);   // 2097152 f2 -> 20971520
    float2* a2p  = (float2*)(ws + 20971520);   // 1048576 f2 -> 23068672
    float2* xft  = (float2*)(ws + 23068672);   // 32768 f2   -> 23134208
    float2* yftp = (float2*)(ws + 23134208);   // 131072 f2  -> 23396352
    float2* b1   = (float2*)(ws + 23396352);   // 262144 f2  -> 23920640
    float*  embk = ws + 23920640;              // 64
    unsigned short* wbh  = (unsigned short*)(ws + 23920704);  // 4096 u16 -> 23922752
    unsigned short* wlbf = (unsigned short*)(ws + 23922752);  // 2048 u16 -> 23923776
    unsigned short* Tinv = (unsigned short*)(ws + 23923776);  // 2048 u16 -> 23924800
    unsigned short* TfT  = (unsigned short*)(ws + 23924800);  // 1024 u16 -> 23925312
    float* Tp1gf = ws + 23925312;              // 1024 f (512 float2)
    float2* Tp1g = (float2*)Tp1gf;

    k_emb<<<2, 256, 0, stream>>>(time_i, conditions, t_embed_w, t_embed_b,
                                 c_embed_w, c_embed_b, lift_b, embk);
    k_wt<<<38, 256, 0, stream>>>(byp_w, lift_w, wbh, wlbf, Tinv, TfT, Tp1gf);
    k_lift<<<8192, 256, 0, stream>>>(state_in, node_pos, wlbf, embk, TfT, xA, a1);

    for (int l = 0; l < 4; l++) {
        unsigned short* xin  = (l & 1) ? xB : xA;
        unsigned short* xout = (l & 1) ? xA : xB;
        const float* wrl = spec_wr + (size_t)l * 524288;
        const float* wil = spec_wi + (size_t)l * 524288;
        k_p1<<<512, 256, 0, stream>>>(a1, Tp1g, a2p);
        k_p2<<<256, 256, 0, stream>>>(a2p, xft);
        k_p3<<<512, 256, 0, stream>>>(xft, wrl, wil, yftp);
        k_p4<<<256, 256, 0, stream>>>(yftp, b1);
        k_fin<<<4096, 256, 0, stream>>>(xin, b1, wbh + l * 1024, byp_b + l * 32,
                                        Tinv, TfT, Tp1g, xout, a1, (l < 3) ? 1 : 0,
                                        (l == 3) ? 1 : 0, state_in,
                                        proj1_w, proj1_b, proj2_w, proj2_b, out);
    }
}

// Round 15
// 366.520 us; speedup vs baseline: 1.0833x; 1.0833x over previous
//
#include <hip/hip_runtime.h>
#include <math.h>

#define PI_F 3.14159265358979323846f

typedef __bf16 bf16x8 __attribute__((ext_vector_type(8)));
typedef float floatx4 __attribute__((ext_vector_type(4)));
union U8 { unsigned short u[8]; uint4 q; bf16x8 v; };

// sigmoid-form GELU: v * sigmoid(1.702 v)
__device__ __forceinline__ float gelu_sig(float v) {
    float e = __builtin_amdgcn_exp2f(-2.4554670f * v);   // exp(-1.702 v)
    return v * __builtin_amdgcn_rcpf(1.0f + e);
}
__device__ __forceinline__ int rfl(int x) { return __builtin_amdgcn_readfirstlane(x); }

__device__ __forceinline__ unsigned short f2bf(float f) {   // RNE fp32->bf16
    unsigned int u = __float_as_uint(f);
    u += 0x7fffu + ((u >> 16) & 1u);
    return (unsigned short)(u >> 16);
}
__device__ __forceinline__ float bf2f(unsigned short h) {
    return __uint_as_float(((unsigned int)h) << 16);
}

// ---------------- emb ----------------
__global__ void k_emb(const float* __restrict__ time_i, const float* __restrict__ conditions,
                      const float* __restrict__ t_embed_w, const float* __restrict__ t_embed_b,
                      const float* __restrict__ c_embed_w, const float* __restrict__ c_embed_b,
                      const float* __restrict__ lift_b, float* __restrict__ embk) {
    __shared__ float red[8][32];
    int t = threadIdx.x;
    int b = blockIdx.x;
    int c = t & 31, lg = t >> 5;
    float acc = 0.0f;
    if (lg == 0) {
        acc = t_embed_b[c] + c_embed_b[c] + lift_b[c];
        float tv = time_i[b];
        float ang = PI_F * tv;
        const float* tw = t_embed_w + c * 11;
        for (int i = 0; i < 5; i++) {
            float s, co; sincosf(ang, &s, &co);
            acc += co * tw[i] + s * tw[5 + i];
            ang *= 2.0f;
        }
        acc += tv * tw[10];
    }
    const float* cw = c_embed_w + c * 352;
    for (int j = 0; j < 4; j++) {
        int l = lg * 4 + j;
        float v = conditions[b * 32 + l];
        float ang = PI_F * v;
        for (int i = 0; i < 5; i++) {
            float s, co; sincosf(ang, &s, &co);
            acc += co * cw[l * 10 + i] + s * cw[l * 10 + 5 + i];
            ang *= 2.0f;
        }
        acc += v * cw[320 + l];
    }
    red[lg][c] = acc;
    __syncthreads();
    if (t < 32) {
        float s = 0.0f;
        for (int g = 0; g < 8; g++) s += red[g][t];
        embk[b * 32 + t] = s;
    }
}

// -------- k_wt: bf16 constants + fp32 uniform-twiddle table Tp1g --------
__global__ void k_wt(const float* __restrict__ byp_w, const float* __restrict__ lift_w,
                     unsigned short* __restrict__ wbh, unsigned short* __restrict__ wlbf,
                     unsigned short* __restrict__ Tinv, unsigned short* __restrict__ TfT,
                     float* __restrict__ Tp1g) {
    int idx = blockIdx.x * 256 + threadIdx.x;
    const float th = PI_F / 32.0f;
    if (idx < 4096) {
        wbh[idx] = f2bf(byp_w[idx]);          // [l][o][i] (A-fragment layout)
    } else if (idx < 6144) {
        int j = idx - 4096;                   // o*64 + q
        int o = j >> 6, q = j & 63;
        wlbf[j] = (q < 37) ? f2bf(lift_w[o * 37 + q]) : 0;
    } else if (idx < 8192) {
        int j = idx - 6144;                   // nz*32 + k
        int nz = j >> 5, k = j & 31;
        int kz = k >> 1;
        float val = 0.0f;
        if (kz < 8) {
            float a = (float)((kz * nz) & 63) * th;
            val = (k & 1) ? sinf(a) : cosf(a);
        }
        Tinv[j] = f2bf(val);
    } else if (idx < 9216) {
        int j = idx - 8192;                   // kcol*64 + nz
        int kcol = j >> 6, nz = j & 63;
        int kz = kcol >> 1;
        float a = (float)((kz * nz) & 63) * th;
        float val = (kcol & 1) ? -sinf(a) : cosf(a);
        TfT[j] = f2bf(val);
    } else if (idx < 9728) {
        int j = idx - 9216;                   // ny*8 + ky
        int ny = j >> 3, ky = j & 7;
        float a = (float)((ky * ny) & 63) * th;
        Tp1g[j * 2] = cosf(a);
        Tp1g[j * 2 + 1] = sinf(a);
    }
}

// XCD swizzle for 8192-block grids
__device__ __forceinline__ void swz8k(int blk, int& b, int& nx, int& ny) {
    int x = blk & 7;
    int j = blk >> 3;
    int pair = x * 16 + (j >> 6);
    ny = j & 63;
    b = pair >> 6;
    nx = pair & 63;
}

// ------- k_lift: MFMA lift conv + emb + MFMA forward z-DFT. x0 in bf16. -------
__global__ __launch_bounds__(256) void k_lift(const float* __restrict__ state_in,
        const float* __restrict__ node_pos, const unsigned short* __restrict__ wlbf,
        const float* __restrict__ embk, const unsigned short* __restrict__ TfT,
        unsigned short* __restrict__ x0, float2* __restrict__ a1) {
    __shared__ __align__(16) float SL[7584];
    unsigned short* fsT  = (unsigned short*)SL;          // [nz][72] u16 (2304 f)
    unsigned short* ysbf = (unsigned short*)(SL + 2304); // [o][72] u16 (1152 f)
    float* pz   = SL + 3456;                             // 4096 f
    float* pz2  = SL + 3456 + 512;                       // 512 f (linear)
    float* bias = SL + 7552;                             // 32
    int t = threadIdx.x;
    int b, nx, ny; swz8k(blockIdx.x, b, nx, ny);
    int nxy = nx * 64 + ny;

    if (t < 32) bias[t] = embk[b * 32 + t];
    {
        for (int u = t; u < 2048; u += 256) {
            int row = u >> 5, col = 37 + (u & 31);
            fsT[row * 72 + col] = 0;
        }
    }
    if (t < 192) {
        int nzf = t / 3;
        int l = t - nzf * 3;
        float p = node_pos[((size_t)b * 262144 + (nxy << 6)) * 3 + t];
        float s, c; sincosf(PI_F * p, &s, &c);
        unsigned short* row = fsT + nzf * 72;
        #pragma unroll
        for (int i = 0; i < 5; i++) {
            row[4 + l * 10 + i] = f2bf(c);
            row[4 + l * 10 + 5 + i] = f2bf(s);
            float nc = 2.0f * c * c - 1.0f;
            s = 2.0f * s * c;
            c = nc;
        }
        row[34 + l] = f2bf(p);
    } else {
        int nzf = t - 192;
        const float4 s4 = *(const float4*)(state_in + ((size_t)b * 262144 + (nxy << 6) + nzf) * 4);
        unsigned short* row = fsT + nzf * 72;
        row[0] = f2bf(s4.x); row[1] = f2bf(s4.y);
        row[2] = f2bf(s4.z); row[3] = f2bf(s4.w);
    }
    __syncthreads();

    int lane = t & 63;
    int w = rfl(t >> 6);
    int otile = w & 1;
    int nzt0 = (w >> 1) * 2;
    int l15 = lane & 15;
    int quad = lane >> 4;

    U8 a0, a1_;
    a0.q = *(const uint4*)(wlbf + ((otile * 16 + l15) << 6) + (quad << 3));
    a1_.q = *(const uint4*)(wlbf + ((otile * 16 + l15) << 6) + 32 + (quad << 3));
    floatx4 cb;
    #pragma unroll
    for (int r = 0; r < 4; r++) cb[r] = bias[otile * 16 + quad * 4 + r];
    floatx4 dz = {0.0f, 0.0f, 0.0f, 0.0f};

    #pragma unroll
    for (int m = 0; m < 2; m++) {
        int nzc = (nzt0 + m) * 16 + l15;
        U8 b0, b1_;
        b0.q = *(const uint4*)(fsT + nzc * 72 + (quad << 3));
        b1_.q = *(const uint4*)(fsT + nzc * 72 + 32 + (quad << 3));
        floatx4 d = __builtin_amdgcn_mfma_f32_16x16x32_bf16(a0.v, b0.v, cb, 0, 0, 0);
        d = __builtin_amdgcn_mfma_f32_16x16x32_bf16(a1_.v, b1_.v, d, 0, 0, 0);
        #pragma unroll
        for (int r = 0; r < 4; r++) {
            int o = otile * 16 + quad * 4 + r;
            ysbf[o * 72 + nzc] = f2bf(d[r]);
        }
    }
    __syncthreads();
    {   // coalesced x0 write
        int ch = t >> 3, q = t & 7;
        uint4 v = *(const uint4*)(ysbf + ch * 72 + q * 8);
        *(uint4*)(x0 + (((size_t)(b * 32 + ch)) << 18) + (nxy << 6) + q * 8) = v;
    }
    {   // forward z-DFT via MFMA: wave (otile, khalf)
        int khalf = w >> 1;
        U8 ay, bt;
        ay.q = *(const uint4*)(ysbf + (otile * 16 + l15) * 72 + khalf * 32 + (quad << 3));
        bt.q = *(const uint4*)(TfT + (l15 << 6) + khalf * 32 + (quad << 3));
        floatx4 d = __builtin_amdgcn_mfma_f32_16x16x32_bf16(ay.v, bt.v, dz, 0, 0, 0);
        *(floatx4*)(pz + w * 1024 + lane * 4) = d;
    }
    __syncthreads();
    if (w < 2) {
        float4 p0 = *(float4*)(pz + w * 1024 + lane * 4);
        float4 p1 = *(float4*)(pz + (w + 2) * 1024 + lane * 4);
        float pv[4] = {p0.x + p1.x, p0.y + p1.y, p0.z + p1.z, p0.w + p1.w};
        #pragma unroll
        for (int r = 0; r < 4; r++)
            pz2[(otile * 16 + quad * 4 + r) * 16 + l15] = pv[r];
    }
    __syncthreads();
    if (t < 128) {
        float4 v = *(float4*)(pz2 + t * 4);
        float* a1f = (float*)a1 + ((size_t)(b * 4096 + nxy)) * 512;
        *(float4*)(a1f + t * 4) = v;
    }
}

// =================== spectral mid-section ===================

// k_p1: forward y-DFT over ny-QUARTERS with uniform-twiddle s_loads. 512 blocks.
__global__ __launch_bounds__(256) void k_p1(const float2* __restrict__ a1,
        const float2* __restrict__ Tp1g, float2* __restrict__ a2p) {
    int blk = blockIdx.x, t = threadIdx.x;
    int x = blk & 7, r = blk >> 3;        // r 0..63
    int pair = x * 16 + (r & 15);
    int qtr = r >> 4;                     // 0..3
    const float2* src = a1 + ((size_t)(pair * 64 + qtr * 16)) * 256 + t;
    float accr[8], acci[8];
    #pragma unroll
    for (int k = 0; k < 8; k++) { accr[k] = 0.0f; acci[k] = 0.0f; }
    #pragma unroll 4
    for (int j = 0; j < 16; j++) {
        int ny = qtr * 16 + j;
        float2 v = src[(size_t)j * 256];
        const float2* tw = Tp1g + ny * 8;    // block-uniform -> s_load
        #pragma unroll
        for (int ky = 0; ky < 8; ky++) {
            float2 w2 = tw[ky];
            accr[ky] += v.x * w2.x + v.y * w2.y;   // e^{-i ky ny θ}
            acci[ky] += v.y * w2.x - v.x * w2.y;
        }
    }
    float4* dst = (float4*)(a2p + (size_t)qtr * 262144 + ((size_t)(pair * 256 + t)) * 8);
    #pragma unroll
    for (int j = 0; j < 4; j++)
        dst[j] = make_float4(accr[2 * j], acci[2 * j], accr[2 * j + 1], acci[2 * j + 1]);
}

// k_p2: forward x-DFT (sums 4 quarter-partials)
__global__ __launch_bounds__(256) void k_p2(const float2* __restrict__ a2p,
                                            float2* __restrict__ xft) {
    __shared__ __align__(16) float2 SH[1040];
    int blk = blockIdx.x, t = threadIdx.x;
    for (int lu = 0; lu < 2; lu++) {
        int un = blk * 2 + lu;
        int b = un >> 8, ckz = un & 255;
        size_t base = (size_t)b * 131072 + (size_t)ckz * 8;
        for (int e = t; e < 512; e += 256) {
            size_t a = base + (size_t)(e >> 3) * 2048 + (e & 7);
            float2 v0 = a2p[a];
            float2 v1 = a2p[a + 262144];
            float2 v2 = a2p[a + 524288];
            float2 v3 = a2p[a + 786432];
            SH[lu * 520 + e] = make_float2(v0.x + v1.x + v2.x + v3.x,
                                           v0.y + v1.y + v2.y + v3.y);
        }
    }
    __syncthreads();
    if (t < 128) {
        int lu = t >> 6, out = t & 63;
        int un = blk * 2 + lu;
        int kx = out & 7;
        float sn, cc; sincosf((float)kx * (PI_F / 32.0f), &sn, &cc);
        float bsn = -sn;
        float tc = 1.0f, ts = 0.0f, rr = 0.0f, ri = 0.0f;
        const float2* row = SH + lu * 520 + (out >> 3);
        for (int nx = 0; nx < 64; nx++) {
            float2 v = row[nx * 8];
            rr += v.x * tc - v.y * ts;
            ri += v.x * ts + v.y * tc;
            float nt = tc * cc - ts * bsn; ts = ts * cc + tc * bsn; tc = nt;
        }
        xft[(size_t)un * 64 + out] = make_float2(rr, ri);
    }
}

// k_p3: mode mix over i-QUARTERS. 512 blocks.
__global__ __launch_bounds__(256) void k_p3(const float2* __restrict__ xft,
        const float* __restrict__ wr, const float* __restrict__ wi,
        float2* __restrict__ yftp) {
    __shared__ __align__(16) float2 SH[64];
    int blk = blockIdx.x, t = threadIdx.x;
    int unit = blk >> 2, iq = blk & 3;
    int b = unit >> 6, kx = (unit >> 3) & 7, ky = unit & 7;
    if (t < 64) {
        int il = t >> 3, kz = t & 7;
        int i = iq * 8 + il;
        SH[t] = xft[((size_t)((b * 32 + i) * 8 + kz)) * 64 + ky * 8 + kx];
    }
    __syncthreads();
    int o = t >> 3, kz = t & 7;
    float yr = 0.0f, yi = 0.0f;
    for (int il = 0; il < 8; il++) {
        int i = iq * 8 + il;
        float2 xv = SH[il * 8 + kz];
        int wofs = ((i * 32 + o) << 9) + kx * 64 + ky * 8 + kz;
        float wrv = wr[wofs], wiv = wi[wofs];
        yr += xv.x * wrv - xv.y * wiv;
        yi += xv.x * wiv + xv.y * wrv;
    }
    yftp[(size_t)iq * 32768 + ((size_t)((b * 32 + o) * 8 + kz)) * 64 + ky * 8 + kx]
        = make_float2(yr, yi);
}

// k_p4: inverse x (sums 4 quarter-partials) -> b1[b][nx][o*8+kz][ky]
__global__ __launch_bounds__(256) void k_p4(const float2* __restrict__ yftp,
                                            float2* __restrict__ b1) {
    __shared__ __align__(16) float2 SH[4608];
    int blk = blockIdx.x, t = threadIdx.x;
    for (int u = 0; u < 2; u++) {
        if (u) __syncthreads();
        int unit = blk * 2 + u;
        int b = unit >> 8, nx = (unit >> 2) & 63, og = unit & 3;
        size_t sbase = ((size_t)(b * 32 + og * 8)) * 512;
        for (int e = t; e < 4096; e += 256) {
            float2 v0 = yftp[sbase + e];
            float2 v1 = yftp[32768 + sbase + e];
            float2 v2 = yftp[65536 + sbase + e];
            float2 v3 = yftp[98304 + sbase + e];
            SH[(e >> 3) * 9 + (e & 7)] = make_float2(v0.x + v1.x + v2.x + v3.x,
                                                     v0.y + v1.y + v2.y + v3.y);
        }
        __syncthreads();
        float cs, ss; sincosf((float)nx * (PI_F / 32.0f), &ss, &cs);
        float2* dst = b1 + ((size_t)(b * 64 + nx)) * 2048 + og * 512;
        for (int h = 0; h < 2; h++) {
            int idx = h * 256 + t;
            const float2* row = SH + idx * 9;
            float c = 1.0f, s = 0.0f, rr = 0.0f, ri = 0.0f;
            #pragma unroll
            for (int kx = 0; kx < 8; kx++) {
                float2 y = row[kx];
                rr += y.x * c - y.y * s;
                ri += y.x * s + y.y * c;
                float nc = c * cs - s * ss; s = s * cs + c * ss; c = nc;
            }
            dst[idx] = make_float2(rr, ri);
        }
    }
}

// ------- k_fin (single column, R13 structure): inverse-y (Tp1g s_load twiddles)
//         + chained MFMA (bypass + inverse-z) + gelu
//         + (l<3) MFMA fwd z-DFT  OR  (l==3) fused proj+residual -------
__global__ __launch_bounds__(256) void k_fin(
        const unsigned short* __restrict__ xin, const float2* __restrict__ b1,
        const unsigned short* __restrict__ wbh, const float* __restrict__ bb,
        const unsigned short* __restrict__ Tinv, const unsigned short* __restrict__ TfT,
        const float2* __restrict__ Tp1g, unsigned short* __restrict__ xout,
        float2* __restrict__ a1, int do_z, int do_proj,
        const float* __restrict__ state_in, const float* __restrict__ p1w,
        const float* __restrict__ p1b, const float* __restrict__ p2w,
        const float* __restrict__ p2b, float* __restrict__ outp) {
    __shared__ __align__(16) float S[7104];
    float* b1sr = S;                              // 2112 (dead after inverse-y)
    float* b1si = S + 2112;                       // 2112 -> 4224
    float* pz   = S;                              // alias (fwd-z sparse, w*1024)
    float* pz2  = S + 512;                        // alias (linear, no overlap w/ pz use)
    float* pr   = S;                              // alias (proj partials)
    unsigned short* xsu  = (unsigned short*)(S + 4224);  // [ch][66] u16 (1056 f)
    unsigned short* msbf = (unsigned short*)(S + 5280);  // [o][40] u16 (640 f)
    unsigned short* ysbf = (unsigned short*)(S + 5920);  // [o][72] u16 (1152 f)
    float* bias = S + 7072;                       // 32
    int t = threadIdx.x;
    int b, nx, ny; swz8k(blockIdx.x, b, nx, ny);
    int nxy = nx * 64 + ny;

    if (t >= 96 && t < 128) bias[t - 96] = bb[t - 96];
    ((unsigned int*)msbf)[(t >> 3) * 20 + 8 + (t & 7)] = 0;   // zero K-pad cols 16..31
    {   // stage x (bf16): one uint4 (8 elems) per thread -> xsu pitch 66
        int ch = t >> 3, q = t & 7;
        uint4 v = *(const uint4*)(xin + (((size_t)b) << 23) + (nxy << 6)
                                  + ((size_t)ch << 18) + q * 8);
        unsigned int* dst = (unsigned int*)(xsu + ch * 66 + q * 8);
        dst[0] = v.x; dst[1] = v.y; dst[2] = v.z; dst[3] = v.w;
    }
    const float2* bsrc = b1 + ((size_t)(b * 64 + nx)) * 2048;   // contiguous 16 KB
    for (int u = 0; u < 8; u++) {
        int g = u * 256 + t;
        float2 v = bsrc[g];
        int ky = g & 7, okz = g >> 3;
        b1sr[ky * 264 + okz] = v.x;
        b1si[ky * 264 + okz] = v.y;
    }
    __syncthreads();
    const float scale = 1.0f / 262144.0f;
    {   // inverse-y (thread t = o*8+kz); twiddles via block-uniform s_loads
        const float2* tw = Tp1g + ny * 8;          // s_load_dwordx*
        float mr = 0.0f, mi = 0.0f;
        #pragma unroll
        for (int ky = 0; ky < 8; ky++) {
            float vr = b1sr[ky * 264 + t], vi = b1si[ky * 264 + t];
            float2 w2 = tw[ky];
            mr += vr * w2.x - vi * w2.y;           // e^{+i ky ny θ}
            mi += vr * w2.y + vi * w2.x;
        }
        int kz = t & 7;
        float sc = (kz == 0) ? scale : 2.0f * scale;
        unsigned int pk = (unsigned int)f2bf(mr * sc)
                        | ((unsigned int)f2bf(-mi * sc) << 16);
        ((unsigned int*)msbf)[(t >> 3) * 20 + kz] = pk;
    }
    __syncthreads();

    // ---- chained MFMA: D = bias + W·X (bypass) + M2·Tinv (inverse-z) ----
    int lane = t & 63;
    int w = rfl(t >> 6);
    int otile = w & 1;
    int nzt0 = (w >> 1) * 2;
    int l15 = lane & 15;
    int quad = lane >> 4;

    U8 aw, ams;
    aw.q = *(const uint4*)(wbh + ((otile * 16 + l15) << 5) + (quad << 3));
    ams.q = *(const uint4*)(msbf + (otile * 16 + l15) * 40 + (quad << 3));
    floatx4 cb;
    #pragma unroll
    for (int r = 0; r < 4; r++) cb[r] = bias[otile * 16 + quad * 4 + r];
    floatx4 dzero = {0.0f, 0.0f, 0.0f, 0.0f};

    size_t colbase = (((size_t)b) << 23) + (nxy << 6);

    #pragma unroll
    for (int m = 0; m < 2; m++) {
        int nzc = (nzt0 + m) * 16 + l15;
        U8 bx, bt;
        #pragma unroll
        for (int j = 0; j < 8; j++) bx.u[j] = xsu[(quad * 8 + j) * 66 + nzc];
        bt.q = *(const uint4*)(Tinv + (nzc << 5) + (quad << 3));   // global, L1-broadcast
        floatx4 d = __builtin_amdgcn_mfma_f32_16x16x32_bf16(aw.v, bx.v, cb, 0, 0, 0);
        d = __builtin_amdgcn_mfma_f32_16x16x32_bf16(ams.v, bt.v, d, 0, 0, 0);
        #pragma unroll
        for (int r = 0; r < 4; r++) {
            int o = otile * 16 + quad * 4 + r;
            ysbf[o * 72 + nzc] = f2bf(gelu_sig(d[r]));
        }
    }
    __syncthreads();

    if (!do_proj) {   // coalesced xout write: one uint4 (8 bf16) per thread
        int ch = t >> 3, q = t & 7;
        uint4 v = *(const uint4*)(ysbf + ch * 72 + q * 8);
        *(uint4*)(xout + colbase + ((size_t)ch << 18) + q * 8) = v;
    }

    if (do_z) {
        int khalf = w >> 1;
        U8 ay, bt;
        ay.q = *(const uint4*)(ysbf + (otile * 16 + l15) * 72 + khalf * 32 + (quad << 3));
        bt.q = *(const uint4*)(TfT + (l15 << 6) + khalf * 32 + (quad << 3));
        floatx4 d = __builtin_amdgcn_mfma_f32_16x16x32_bf16(ay.v, bt.v, dzero, 0, 0, 0);
        *(floatx4*)(pz + w * 1024 + lane * 4) = d;
        __syncthreads();
        if (w < 2) {
            float4 p0 = *(float4*)(pz + w * 1024 + lane * 4);
            float4 p1 = *(float4*)(pz + (w + 2) * 1024 + lane * 4);
            float pv[4] = {p0.x + p1.x, p0.y + p1.y, p0.z + p1.z, p0.w + p1.w};
            #pragma unroll
            for (int r = 0; r < 4; r++)
                pz2[(otile * 16 + quad * 4 + r) * 16 + l15] = pv[r];  // conflict-free
        }
        __syncthreads();
        if (t < 128) {
            float4 v = *(float4*)(pz2 + t * 4);
            float* a1f = (float*)a1 + ((size_t)(b * 4096 + nxy)) * 512;
            *(float4*)(a1f + t * 4) = v;                              // coalesced 2 KB
        }
    }

    if (do_proj) {                  // fused proj1 -> gelu -> proj2 -> residual
        int nz = t & 63;
        float xv[32];
        #pragma unroll
        for (int i = 0; i < 32; i++) xv[i] = bf2f(ysbf[i * 72 + nz]);
        float r0 = 0.f, r1 = 0.f, r2 = 0.f, r3 = 0.f;
        #pragma unroll
        for (int k = 0; k < 8; k++) {
            int o = w * 8 + k;
            float a = p1b[o];                                   // s_load
            const float* wr = p1w + o * 32;                     // s_load
            #pragma unroll
            for (int i = 0; i < 32; i++) a += wr[i] * xv[i];
            float h = gelu_sig(a);
            r0 += p2w[0 * 32 + o] * h;
            r1 += p2w[1 * 32 + o] * h;
            r2 += p2w[2 * 32 + o] * h;
            r3 += p2w[3 * 32 + o] * h;
        }
        *(float4*)(pr + w * 256 + nz * 4) = make_float4(r0, r1, r2, r3);
        __syncthreads();
        if (t < 64) {
            float4 a0 = *(float4*)(pr + 0 * 256 + t * 4);
            float4 a1_ = *(float4*)(pr + 1 * 256 + t * 4);
            float4 a2 = *(float4*)(pr + 2 * 256 + t * 4);
            float4 a3 = *(float4*)(pr + 3 * 256 + t * 4);
            size_t base = ((size_t)b * 262144 + (nxy << 6) + t) * 4;
            float4 sv = *(const float4*)(state_in + base);
            *(float4*)(outp + base) = make_float4(
                sv.x + 0.05f * (p2b[0] + a0.x + a1_.x + a2.x + a3.x),
                sv.y + 0.05f * (p2b[1] + a0.y + a1_.y + a2.y + a3.y),
                sv.z + 0.05f * (p2b[2] + a0.z + a1_.z + a2.z + a3.z),
                sv.w + 0.05f * (p2b[3] + a0.w + a1_.w + a2.w + a3.w));
        }
    }
}

extern "C" void kernel_launch(void* const* d_in, const int* in_sizes, int n_in,
                              void* d_out, int out_size, void* d_ws, size_t ws_size,
                              hipStream_t stream) {
    const float* state_in   = (const float*)d_in[0];
    const float* node_pos   = (const float*)d_in[1];
    const float* time_i     = (const float*)d_in[3];
    const float* conditions = (const float*)d_in[4];
    const float* t_embed_w  = (const float*)d_in[5];
    const float* t_embed_b  = (const float*)d_in[6];
    const float* c_embed_w  = (const float*)d_in[7];
    const float* c_embed_b  = (const float*)d_in[8];
    const float* lift_w     = (const float*)d_in[9];
    const float* lift_b     = (const float*)d_in[10];
    const float* spec_wr    = (const float*)d_in[11];
    const float* spec_wi    = (const float*)d_in[12];
    const float* byp_w      = (const float*)d_in[13];
    const float* byp_b      = (const float*)d_in[14];
    const float* proj1_w    = (const float*)d_in[15];
    const float* proj1_b    = (const float*)d_in[16];
    const float* proj2_w    = (const float*)d_in[17];
    const float* proj2_b    = (const float*)d_in[18];
    float* out = (float*)d_out;
    float* ws  = (float*)d_ws;

    unsigned short* xA = (unsigned short*)ws;                 // 16777216 u16
    unsigned short* xB = (unsigned short*)(ws + 8388608);     // 16777216 u16
    float2* a1   = (float2*)(ws + 16777216);   // 2097152 f2 -> 20971520
    float2* a2p  = (float2*)(ws + 20971520);   // 1048576 f2 -> 23068672
    float2* xft  = (float2*)(ws + 23068672);   // 32768 f2   -> 23134208
    float2* yftp = (float2*)(ws + 23134208);   // 131072 f2  -> 23396352
    float2* b1   = (float2*)(ws + 23396352);   // 262144 f2  -> 23920640
    float*  embk = ws + 23920640;              // 64
    unsigned short* wbh  = (unsigned short*)(ws + 23920704);  // 4096 u16 -> 23922752
    unsigned short* wlbf = (unsigned short*)(ws + 23922752);  // 2048 u16 -> 23923776
    unsigned short* Tinv = (unsigned short*)(ws + 23923776);  // 2048 u16 -> 23924800
    unsigned short* TfT  = (unsigned short*)(ws + 23924800);  // 1024 u16 -> 23925312
    float* Tp1gf = ws + 23925312;              // 1024 f (512 float2)
    float2* Tp1g = (float2*)Tp1gf;

    k_emb<<<2, 256, 0, stream>>>(time_i, conditions, t_embed_w, t_embed_b,
                                 c_embed_w, c_embed_b, lift_b, embk);
    k_wt<<<38, 256, 0, stream>>>(byp_w, lift_w, wbh, wlbf, Tinv, TfT, Tp1gf);
    k_lift<<<8192, 256, 0, stream>>>(state_in, node_pos, wlbf, embk, TfT, xA, a1);

    for (int l = 0; l < 4; l++) {
        unsigned short* xin  = (l & 1) ? xB : xA;
        unsigned short* xout = (l & 1) ? xA : xB;
        const float* wrl = spec_wr + (size_t)l * 524288;
        const float* wil = spec_wi + (size_t)l * 524288;
        k_p1<<<512, 256, 0, stream>>>(a1, Tp1g, a2p);
        k_p2<<<256, 256, 0, stream>>>(a2p, xft);
        k_p3<<<512, 256, 0, stream>>>(xft, wrl, wil, yftp);
        k_p4<<<256, 256, 0, stream>>>(yftp, b1);
        k_fin<<<8192, 256, 0, stream>>>(xin, b1, wbh + l * 1024, byp_b + l * 32,
                                        Tinv, TfT, Tp1g, xout, a1, (l < 3) ? 1 : 0,
                                        (l == 3) ? 1 : 0, state_in,
                                        proj1_w, proj1_b, proj2_w, proj2_b, out);
    }
}

// Round 16
// 344.906 us; speedup vs baseline: 1.1512x; 1.0627x over previous
//
#include <hip/hip_runtime.h>
#include <math.h>

#define PI_F 3.14159265358979323846f

typedef __bf16 bf16x8 __attribute__((ext_vector_type(8)));
typedef float floatx4 __attribute__((ext_vector_type(4)));
union U8 { unsigned short u[8]; uint4 q; bf16x8 v; };

// sigmoid-form GELU: v * sigmoid(1.702 v)
__device__ __forceinline__ float gelu_sig(float v) {
    float e = __builtin_amdgcn_exp2f(-2.4554670f * v);   // exp(-1.702 v)
    return v * __builtin_amdgcn_rcpf(1.0f + e);
}
__device__ __forceinline__ int rfl(int x) { return __builtin_amdgcn_readfirstlane(x); }

__device__ __forceinline__ unsigned short f2bf(float f) {   // RNE fp32->bf16
    unsigned int u = __float_as_uint(f);
    u += 0x7fffu + ((u >> 16) & 1u);
    return (unsigned short)(u >> 16);
}
__device__ __forceinline__ float bf2f(unsigned short h) {
    return __uint_as_float(((unsigned int)h) << 16);
}

// ---------------- emb ----------------
__global__ void k_emb(const float* __restrict__ time_i, const float* __restrict__ conditions,
                      const float* __restrict__ t_embed_w, const float* __restrict__ t_embed_b,
                      const float* __restrict__ c_embed_w, const float* __restrict__ c_embed_b,
                      const float* __restrict__ lift_b, float* __restrict__ embk) {
    __shared__ float red[8][32];
    int t = threadIdx.x;
    int b = blockIdx.x;
    int c = t & 31, lg = t >> 5;
    float acc = 0.0f;
    if (lg == 0) {
        acc = t_embed_b[c] + c_embed_b[c] + lift_b[c];
        float tv = time_i[b];
        float ang = PI_F * tv;
        const float* tw = t_embed_w + c * 11;
        for (int i = 0; i < 5; i++) {
            float s, co; sincosf(ang, &s, &co);
            acc += co * tw[i] + s * tw[5 + i];
            ang *= 2.0f;
        }
        acc += tv * tw[10];
    }
    const float* cw = c_embed_w + c * 352;
    for (int j = 0; j < 4; j++) {
        int l = lg * 4 + j;
        float v = conditions[b * 32 + l];
        float ang = PI_F * v;
        for (int i = 0; i < 5; i++) {
            float s, co; sincosf(ang, &s, &co);
            acc += co * cw[l * 10 + i] + s * cw[l * 10 + 5 + i];
            ang *= 2.0f;
        }
        acc += v * cw[320 + l];
    }
    red[lg][c] = acc;
    __syncthreads();
    if (t < 32) {
        float s = 0.0f;
        for (int g = 0; g < 8; g++) s += red[g][t];
        embk[b * 32 + t] = s;
    }
}

// -------- k_wt: bf16 constants (scale folded into Tinv) + fp32 twiddle table Tp1g --------
__global__ void k_wt(const float* __restrict__ byp_w, const float* __restrict__ lift_w,
                     unsigned short* __restrict__ wbh, unsigned short* __restrict__ wlbf,
                     unsigned short* __restrict__ Tinv, unsigned short* __restrict__ TfT,
                     float* __restrict__ Tp1g) {
    int idx = blockIdx.x * 256 + threadIdx.x;
    const float th = PI_F / 32.0f;
    if (idx < 4096) {
        wbh[idx] = f2bf(byp_w[idx]);          // [l][o][i] (A-fragment layout)
    } else if (idx < 6144) {
        int j = idx - 4096;                   // o*64 + q
        int o = j >> 6, q = j & 63;
        wlbf[j] = (q < 37) ? f2bf(lift_w[o * 37 + q]) : 0;
    } else if (idx < 8192) {
        int j = idx - 6144;                   // nz*32 + k
        int nz = j >> 5, k = j & 31;
        int kz = k >> 1;
        float val = 0.0f;
        if (kz < 8) {
            float a = (float)((kz * nz) & 63) * th;
            val = (k & 1) ? sinf(a) : cosf(a);
            val *= (kz == 0) ? (1.0f / 262144.0f) : (2.0f / 262144.0f);   // fold scale
        }
        Tinv[j] = f2bf(val);
    } else if (idx < 9216) {
        int j = idx - 8192;                   // kcol*64 + nz
        int kcol = j >> 6, nz = j & 63;
        int kz = kcol >> 1;
        float a = (float)((kz * nz) & 63) * th;
        float val = (kcol & 1) ? -sinf(a) : cosf(a);
        TfT[j] = f2bf(val);
    } else if (idx < 9728) {
        int j = idx - 9216;                   // ny*8 + ky
        int ny = j >> 3, ky = j & 7;
        float a = (float)((ky * ny) & 63) * th;
        Tp1g[j * 2] = cosf(a);
        Tp1g[j * 2 + 1] = sinf(a);
    }
}

// XCD swizzle for 8192-block grids
__device__ __forceinline__ void swz8k(int blk, int& b, int& nx, int& ny) {
    int x = blk & 7;
    int j = blk >> 3;
    int pair = x * 16 + (j >> 6);
    ny = j & 63;
    b = pair >> 6;
    nx = pair & 63;
}

// ------- k_lift: MFMA lift conv + emb + MFMA forward z-DFT. x0 in bf16. -------
__global__ __launch_bounds__(256) void k_lift(const float* __restrict__ state_in,
        const float* __restrict__ node_pos, const unsigned short* __restrict__ wlbf,
        const float* __restrict__ embk, const unsigned short* __restrict__ TfT,
        unsigned short* __restrict__ x0, float2* __restrict__ a1) {
    __shared__ __align__(16) float SL[5024];
    unsigned short* fsT  = (unsigned short*)SL;          // [nz][72] u16 (2304 f)
    unsigned short* ysbf = (unsigned short*)(SL + 2304); // [o][72] u16 (1152 f)
    float* pz   = SL + 3456;                             // 1024 f (compact)
    float* pz2  = SL + 4480;                             // 512 f (linear)
    float* bias = SL + 4992;                             // 32
    int t = threadIdx.x;
    int b, nx, ny; swz8k(blockIdx.x, b, nx, ny);
    int nxy = nx * 64 + ny;

    if (t < 32) bias[t] = embk[b * 32 + t];
    {
        for (int u = t; u < 2048; u += 256) {
            int row = u >> 5, col = 37 + (u & 31);
            fsT[row * 72 + col] = 0;
        }
    }
    if (t < 192) {
        int nzf = t / 3;
        int l = t - nzf * 3;
        float p = node_pos[((size_t)b * 262144 + (nxy << 6)) * 3 + t];
        float s, c; sincosf(PI_F * p, &s, &c);
        unsigned short* row = fsT + nzf * 72;
        #pragma unroll
        for (int i = 0; i < 5; i++) {
            row[4 + l * 10 + i] = f2bf(c);
            row[4 + l * 10 + 5 + i] = f2bf(s);
            float nc = 2.0f * c * c - 1.0f;
            s = 2.0f * s * c;
            c = nc;
        }
        row[34 + l] = f2bf(p);
    } else {
        int nzf = t - 192;
        const float4 s4 = *(const float4*)(state_in + ((size_t)b * 262144 + (nxy << 6) + nzf) * 4);
        unsigned short* row = fsT + nzf * 72;
        row[0] = f2bf(s4.x); row[1] = f2bf(s4.y);
        row[2] = f2bf(s4.z); row[3] = f2bf(s4.w);
    }
    __syncthreads();

    int lane = t & 63;
    int w = rfl(t >> 6);
    int otile = w & 1;
    int nzt0 = (w >> 1) * 2;
    int l15 = lane & 15;
    int quad = lane >> 4;

    U8 a0, a1_;
    a0.q = *(const uint4*)(wlbf + ((otile * 16 + l15) << 6) + (quad << 3));
    a1_.q = *(const uint4*)(wlbf + ((otile * 16 + l15) << 6) + 32 + (quad << 3));
    floatx4 cb;
    #pragma unroll
    for (int r = 0; r < 4; r++) cb[r] = bias[otile * 16 + quad * 4 + r];
    floatx4 dz = {0.0f, 0.0f, 0.0f, 0.0f};

    #pragma unroll
    for (int m = 0; m < 2; m++) {
        int nzc = (nzt0 + m) * 16 + l15;
        U8 b0, b1_;
        b0.q = *(const uint4*)(fsT + nzc * 72 + (quad << 3));
        b1_.q = *(const uint4*)(fsT + nzc * 72 + 32 + (quad << 3));
        floatx4 d = __builtin_amdgcn_mfma_f32_16x16x32_bf16(a0.v, b0.v, cb, 0, 0, 0);
        d = __builtin_amdgcn_mfma_f32_16x16x32_bf16(a1_.v, b1_.v, d, 0, 0, 0);
        #pragma unroll
        for (int r = 0; r < 4; r++) {
            int o = otile * 16 + quad * 4 + r;
            ysbf[o * 72 + nzc] = f2bf(d[r]);
        }
    }
    __syncthreads();
    {   // coalesced x0 write
        int ch = t >> 3, q = t & 7;
        uint4 v = *(const uint4*)(ysbf + ch * 72 + q * 8);
        *(uint4*)(x0 + (((size_t)(b * 32 + ch)) << 18) + (nxy << 6) + q * 8) = v;
    }
    {   // forward z-DFT via MFMA: wave (otile, khalf)
        int khalf = w >> 1;
        U8 ay, bt;
        ay.q = *(const uint4*)(ysbf + (otile * 16 + l15) * 72 + khalf * 32 + (quad << 3));
        bt.q = *(const uint4*)(TfT + (l15 << 6) + khalf * 32 + (quad << 3));
        floatx4 d = __builtin_amdgcn_mfma_f32_16x16x32_bf16(ay.v, bt.v, dz, 0, 0, 0);
        *(floatx4*)(pz + w * 256 + lane * 4) = d;
    }
    __syncthreads();
    if (w < 2) {
        float4 p0 = *(float4*)(pz + w * 256 + lane * 4);
        float4 p1 = *(float4*)(pz + (w + 2) * 256 + lane * 4);
        float pv[4] = {p0.x + p1.x, p0.y + p1.y, p0.z + p1.z, p0.w + p1.w};
        #pragma unroll
        for (int r = 0; r < 4; r++)
            pz2[(otile * 16 + quad * 4 + r) * 16 + l15] = pv[r];
    }
    __syncthreads();
    if (t < 128) {
        float4 v = *(float4*)(pz2 + t * 4);
        float* a1f = (float*)a1 + ((size_t)(b * 4096 + nxy)) * 512;
        *(float4*)(a1f + t * 4) = v;
    }
}

// =================== spectral mid-section ===================

// k_p1: forward y-DFT over ny-QUARTERS with uniform-twiddle s_loads. 512 blocks.
__global__ __launch_bounds__(256) void k_p1(const float2* __restrict__ a1,
        const float2* __restrict__ Tp1g, float2* __restrict__ a2p) {
    int blk = blockIdx.x, t = threadIdx.x;
    int x = blk & 7, r = blk >> 3;        // r 0..63
    int pair = x * 16 + (r & 15);
    int qtr = r >> 4;                     // 0..3
    const float2* src = a1 + ((size_t)(pair * 64 + qtr * 16)) * 256 + t;
    float accr[8], acci[8];
    #pragma unroll
    for (int k = 0; k < 8; k++) { accr[k] = 0.0f; acci[k] = 0.0f; }
    #pragma unroll 4
    for (int j = 0; j < 16; j++) {
        int ny = qtr * 16 + j;
        float2 v = src[(size_t)j * 256];
        const float2* tw = Tp1g + ny * 8;    // block-uniform -> s_load
        #pragma unroll
        for (int ky = 0; ky < 8; ky++) {
            float2 w2 = tw[ky];
            accr[ky] += v.x * w2.x + v.y * w2.y;   // e^{-i ky ny θ}
            acci[ky] += v.y * w2.x - v.x * w2.y;
        }
    }
    float4* dst = (float4*)(a2p + (size_t)qtr * 262144 + ((size_t)(pair * 256 + t)) * 8);
    #pragma unroll
    for (int j = 0; j < 4; j++)
        dst[j] = make_float4(accr[2 * j], acci[2 * j], accr[2 * j + 1], acci[2 * j + 1]);
}

// k_p2: forward x-DFT (sums 4 quarter-partials)
__global__ __launch_bounds__(256) void k_p2(const float2* __restrict__ a2p,
                                            float2* __restrict__ xft) {
    __shared__ __align__(16) float2 SH[1040];
    int blk = blockIdx.x, t = threadIdx.x;
    for (int lu = 0; lu < 2; lu++) {
        int un = blk * 2 + lu;
        int b = un >> 8, ckz = un & 255;
        size_t base = (size_t)b * 131072 + (size_t)ckz * 8;
        for (int e = t; e < 512; e += 256) {
            size_t a = base + (size_t)(e >> 3) * 2048 + (e & 7);
            float2 v0 = a2p[a];
            float2 v1 = a2p[a + 262144];
            float2 v2 = a2p[a + 524288];
            float2 v3 = a2p[a + 786432];
            SH[lu * 520 + e] = make_float2(v0.x + v1.x + v2.x + v3.x,
                                           v0.y + v1.y + v2.y + v3.y);
        }
    }
    __syncthreads();
    if (t < 128) {
        int lu = t >> 6, out = t & 63;
        int un = blk * 2 + lu;
        int kx = out & 7;
        float sn, cc; sincosf((float)kx * (PI_F / 32.0f), &sn, &cc);
        float bsn = -sn;
        float tc = 1.0f, ts = 0.0f, rr = 0.0f, ri = 0.0f;
        const float2* row = SH + lu * 520 + (out >> 3);
        for (int nx = 0; nx < 64; nx++) {
            float2 v = row[nx * 8];
            rr += v.x * tc - v.y * ts;
            ri += v.x * ts + v.y * tc;
            float nt = tc * cc - ts * bsn; ts = ts * cc + tc * bsn; tc = nt;
        }
        xft[(size_t)un * 64 + out] = make_float2(rr, ri);
    }
}

// k_p3: mode mix over i-QUARTERS. 512 blocks.
__global__ __launch_bounds__(256) void k_p3(const float2* __restrict__ xft,
        const float* __restrict__ wr, const float* __restrict__ wi,
        float2* __restrict__ yftp) {
    __shared__ __align__(16) float2 SH[64];
    int blk = blockIdx.x, t = threadIdx.x;
    int unit = blk >> 2, iq = blk & 3;
    int b = unit >> 6, kx = (unit >> 3) & 7, ky = unit & 7;
    if (t < 64) {
        int il = t >> 3, kz = t & 7;
        int i = iq * 8 + il;
        SH[t] = xft[((size_t)((b * 32 + i) * 8 + kz)) * 64 + ky * 8 + kx];
    }
    __syncthreads();
    int o = t >> 3, kz = t & 7;
    float yr = 0.0f, yi = 0.0f;
    for (int il = 0; il < 8; il++) {
        int i = iq * 8 + il;
        float2 xv = SH[il * 8 + kz];
        int wofs = ((i * 32 + o) << 9) + kx * 64 + ky * 8 + kz;
        float wrv = wr[wofs], wiv = wi[wofs];
        yr += xv.x * wrv - xv.y * wiv;
        yi += xv.x * wiv + xv.y * wrv;
    }
    yftp[(size_t)iq * 32768 + ((size_t)((b * 32 + o) * 8 + kz)) * 64 + ky * 8 + kx]
        = make_float2(yr, yi);
}

// k_p4: inverse x (sums 4 quarter-partials) -> b1[b][nx][o*8+kz][ky]
__global__ __launch_bounds__(256) void k_p4(const float2* __restrict__ yftp,
                                            float2* __restrict__ b1) {
    __shared__ __align__(16) float2 SH[4608];
    int blk = blockIdx.x, t = threadIdx.x;
    for (int u = 0; u < 2; u++) {
        if (u) __syncthreads();
        int unit = blk * 2 + u;
        int b = unit >> 8, nx = (unit >> 2) & 63, og = unit & 3;
        size_t sbase = ((size_t)(b * 32 + og * 8)) * 512;
        for (int e = t; e < 4096; e += 256) {
            float2 v0 = yftp[sbase + e];
            float2 v1 = yftp[32768 + sbase + e];
            float2 v2 = yftp[65536 + sbase + e];
            float2 v3 = yftp[98304 + sbase + e];
            SH[(e >> 3) * 9 + (e & 7)] = make_float2(v0.x + v1.x + v2.x + v3.x,
                                                     v0.y + v1.y + v2.y + v3.y);
        }
        __syncthreads();
        float cs, ss; sincosf((float)nx * (PI_F / 32.0f), &ss, &cs);
        float2* dst = b1 + ((size_t)(b * 64 + nx)) * 2048 + og * 512;
        for (int h = 0; h < 2; h++) {
            int idx = h * 256 + t;
            const float2* row = SH + idx * 9;
            float c = 1.0f, s = 0.0f, rr = 0.0f, ri = 0.0f;
            #pragma unroll
            for (int kx = 0; kx < 8; kx++) {
                float2 y = row[kx];
                rr += y.x * c - y.y * s;
                ri += y.x * s + y.y * c;
                float nc = c * cs - s * ss; s = s * cs + c * ss; c = nc;
            }
            dst[idx] = make_float2(rr, ri);
        }
    }
}

// ------- k_fin: register inverse-y (direct global b1 read, s_load twiddles)
//         + chained MFMA (bypass + inverse-z) + gelu
//         + (l<3) MFMA fwd z-DFT  OR  (l==3) fused proj+residual -------
__global__ __launch_bounds__(256) void k_fin(
        const unsigned short* __restrict__ xin, const float2* __restrict__ b1,
        const unsigned short* __restrict__ wbh, const float* __restrict__ bb,
        const unsigned short* __restrict__ Tinv, const unsigned short* __restrict__ TfT,
        const float2* __restrict__ Tp1g, unsigned short* __restrict__ xout,
        float2* __restrict__ a1, int do_z, int do_proj,
        const float* __restrict__ state_in, const float* __restrict__ p1w,
        const float* __restrict__ p1b, const float* __restrict__ p2w,
        const float* __restrict__ p2b, float* __restrict__ outp) {
    __shared__ __align__(16) float S[4416];
    float* pz   = S;                              // 1024 (fwd-z compact partials)
    float* pz2  = S + 1024;                       // 512 (linear)
    float* pr   = S;                              // 1024 alias (proj partials)
    unsigned short* xsu  = (unsigned short*)(S + 1536);  // [ch][66] u16 (1056 f)
    unsigned short* msbf = (unsigned short*)(S + 2592);  // [o][40] u16 (640 f)
    unsigned short* ysbf = (unsigned short*)(S + 3232);  // [o][72] u16 (1152 f)
    float* bias = S + 4384;                       // 32
    int t = threadIdx.x;
    int b, nx, ny; swz8k(blockIdx.x, b, nx, ny);
    int nxy = nx * 64 + ny;

    if (t >= 96 && t < 128) bias[t - 96] = bb[t - 96];
    ((unsigned int*)msbf)[(t >> 3) * 20 + 8 + (t & 7)] = 0;   // zero K-pad cols 16..31
    {   // stage x (bf16): one uint4 (8 elems) per thread -> xsu pitch 66
        int ch = t >> 3, q = t & 7;
        uint4 v = *(const uint4*)(xin + (((size_t)b) << 23) + (nxy << 6)
                                  + ((size_t)ch << 18) + q * 8);
        unsigned int* dst = (unsigned int*)(xsu + ch * 66 + q * 8);
        dst[0] = v.x; dst[1] = v.y; dst[2] = v.z; dst[3] = v.w;
    }
    {   // inverse-y fully in registers: thread t reads its contiguous 64 B b1 row
        const float4* g = (const float4*)(b1 + ((size_t)(b * 64 + nx)) * 2048
                                          + (size_t)t * 8);
        float4 g0 = g[0], g1 = g[1], g2 = g[2], g3 = g[3];
        float vr[8], vi[8];
        vr[0] = g0.x; vi[0] = g0.y; vr[1] = g0.z; vi[1] = g0.w;
        vr[2] = g1.x; vi[2] = g1.y; vr[3] = g1.z; vi[3] = g1.w;
        vr[4] = g2.x; vi[4] = g2.y; vr[5] = g2.z; vi[5] = g2.w;
        vr[6] = g3.x; vi[6] = g3.y; vr[7] = g3.z; vi[7] = g3.w;
        const float2* tw = Tp1g + ny * 8;          // block-uniform -> s_load
        float mr = 0.0f, mi = 0.0f;
        #pragma unroll
        for (int ky = 0; ky < 8; ky++) {
            float2 w2 = tw[ky];
            mr += vr[ky] * w2.x - vi[ky] * w2.y;   // e^{+i ky ny θ}
            mi += vr[ky] * w2.y + vi[ky] * w2.x;
        }
        unsigned int pk = (unsigned int)f2bf(mr)
                        | ((unsigned int)f2bf(-mi) << 16);
        ((unsigned int*)msbf)[(t >> 3) * 20 + (t & 7)] = pk;
    }
    __syncthreads();

    // ---- chained MFMA: D = bias + W·X (bypass) + M2·Tinv (inverse-z, scale in Tinv) ----
    int lane = t & 63;
    int w = rfl(t >> 6);
    int otile = w & 1;
    int nzt0 = (w >> 1) * 2;
    int l15 = lane & 15;
    int quad = lane >> 4;

    U8 aw, ams;
    aw.q = *(const uint4*)(wbh + ((otile * 16 + l15) << 5) + (quad << 3));
    ams.q = *(const uint4*)(msbf + (otile * 16 + l15) * 40 + (quad << 3));
    floatx4 cb;
    #pragma unroll
    for (int r = 0; r < 4; r++) cb[r] = bias[otile * 16 + quad * 4 + r];
    floatx4 dzero = {0.0f, 0.0f, 0.0f, 0.0f};

    size_t colbase = (((size_t)b) << 23) + (nxy << 6);

    #pragma unroll
    for (int m = 0; m < 2; m++) {
        int nzc = (nzt0 + m) * 16 + l15;
        U8 bx, bt;
        #pragma unroll
        for (int j = 0; j < 8; j++) bx.u[j] = xsu[(quad * 8 + j) * 66 + nzc];
        bt.q = *(const uint4*)(Tinv + (nzc << 5) + (quad << 3));   // global, L1-broadcast
        floatx4 d = __builtin_amdgcn_mfma_f32_16x16x32_bf16(aw.v, bx.v, cb, 0, 0, 0);
        d = __builtin_amdgcn_mfma_f32_16x16x32_bf16(ams.v, bt.v, d, 0, 0, 0);
        #pragma unroll
        for (int r = 0; r < 4; r++) {
            int o = otile * 16 + quad * 4 + r;
            ysbf[o * 72 + nzc] = f2bf(gelu_sig(d[r]));
        }
    }
    __syncthreads();

    if (!do_proj) {   // coalesced xout write: one uint4 (8 bf16) per thread
        int ch = t >> 3, q = t & 7;
        uint4 v = *(const uint4*)(ysbf + ch * 72 + q * 8);
        *(uint4*)(xout + colbase + ((size_t)ch << 18) + q * 8) = v;
    }

    if (do_z) {
        int khalf = w >> 1;
        U8 ay, bt;
        ay.q = *(const uint4*)(ysbf + (otile * 16 + l15) * 72 + khalf * 32 + (quad << 3));
        bt.q = *(const uint4*)(TfT + (l15 << 6) + khalf * 32 + (quad << 3));
        floatx4 d = __builtin_amdgcn_mfma_f32_16x16x32_bf16(ay.v, bt.v, dzero, 0, 0, 0);
        *(floatx4*)(pz + w * 256 + lane * 4) = d;
        __syncthreads();
        if (w < 2) {
            float4 p0 = *(float4*)(pz + w * 256 + lane * 4);
            float4 p1 = *(float4*)(pz + (w + 2) * 256 + lane * 4);
            float pv[4] = {p0.x + p1.x, p0.y + p1.y, p0.z + p1.z, p0.w + p1.w};
            #pragma unroll
            for (int r = 0; r < 4; r++)
                pz2[(otile * 16 + quad * 4 + r) * 16 + l15] = pv[r];
        }
        __syncthreads();
        if (t < 128) {
            float4 v = *(float4*)(pz2 + t * 4);
            float* a1f = (float*)a1 + ((size_t)(b * 4096 + nxy)) * 512;
            *(float4*)(a1f + t * 4) = v;                              // coalesced 2 KB
        }
    }

    if (do_proj) {                  // fused proj1 -> gelu -> proj2 -> residual
        int nz = t & 63;
        float xv[32];
        #pragma unroll
        for (int i = 0; i < 32; i++) xv[i] = bf2f(ysbf[i * 72 + nz]);
        float r0 = 0.f, r1 = 0.f, r2 = 0.f, r3 = 0.f;
        #pragma unroll
        for (int k = 0; k < 8; k++) {
            int o = w * 8 + k;
            float a = p1b[o];                                   // s_load
            const float* wr = p1w + o * 32;                     // s_load
            #pragma unroll
            for (int i = 0; i < 32; i++) a += wr[i] * xv[i];
            float h = gelu_sig(a);
            r0 += p2w[0 * 32 + o] * h;
            r1 += p2w[1 * 32 + o] * h;
            r2 += p2w[2 * 32 + o] * h;
            r3 += p2w[3 * 32 + o] * h;
        }
        *(float4*)(pr + w * 256 + nz * 4) = make_float4(r0, r1, r2, r3);
        __syncthreads();
        if (t < 64) {
            float4 a0 = *(float4*)(pr + 0 * 256 + t * 4);
            float4 a1_ = *(float4*)(pr + 1 * 256 + t * 4);
            float4 a2 = *(float4*)(pr + 2 * 256 + t * 4);
            float4 a3 = *(float4*)(pr + 3 * 256 + t * 4);
            size_t base = ((size_t)b * 262144 + (nxy << 6) + t) * 4;
            float4 sv = *(const float4*)(state_in + base);
            *(float4*)(outp + base) = make_float4(
                sv.x + 0.05f * (p2b[0] + a0.x + a1_.x + a2.x + a3.x),
                sv.y + 0.05f * (p2b[1] + a0.y + a1_.y + a2.y + a3.y),
                sv.z + 0.05f * (p2b[2] + a0.z + a1_.z + a2.z + a3.z),
                sv.w + 0.05f * (p2b[3] + a0.w + a1_.w + a2.w + a3.w));
        }
    }
}

extern "C" void kernel_launch(void* const* d_in, const int* in_sizes, int n_in,
                              void* d_out, int out_size, void* d_ws, size_t ws_size,
                              hipStream_t stream) {
    const float* state_in   = (const float*)d_in[0];
    const float* node_pos   = (const float*)d_in[1];
    const float* time_i     = (const float*)d_in[3];
    const float* conditions = (const float*)d_in[4];
    const float* t_embed_w  = (const float*)d_in[5];
    const float* t_embed_b  = (const float*)d_in[6];
    const float* c_embed_w  = (const float*)d_in[7];
    const float* c_embed_b  = (const float*)d_in[8];
    const float* lift_w     = (const float*)d_in[9];
    const float* lift_b     = (const float*)d_in[10];
    const float* spec_wr    = (const float*)d_in[11];
    const float* spec_wi    = (const float*)d_in[12];
    const float* byp_w      = (const float*)d_in[13];
    const float* byp_b      = (const float*)d_in[14];
    const float* proj1_w    = (const float*)d_in[15];
    const float* proj1_b    = (const float*)d_in[16];
    const float* proj2_w    = (const float*)d_in[17];
    const float* proj2_b    = (const float*)d_in[18];
    float* out = (float*)d_out;
    float* ws  = (float*)d_ws;

    unsigned short* xA = (unsigned short*)ws;                 // 16777216 u16
    unsigned short* xB = (unsigned short*)(ws + 8388608);     // 16777216 u16
    float2* a1   = (float2*)(ws + 16777216);   // 2097152 f2 -> 20971520
    float2* a2p  = (float2*)(ws + 20971520);   // 1048576 f2 -> 23068672
    float2* xft  = (float2*)(ws + 23068672);   // 32768 f2   -> 23134208
    float2* yftp = (float2*)(ws + 23134208);   // 131072 f2  -> 23396352
    float2* b1   = (float2*)(ws + 23396352);   // 262144 f2  -> 23920640
    float*  embk = ws + 23920640;              // 64
    unsigned short* wbh  = (unsigned short*)(ws + 23920704);  // 4096 u16 -> 23922752
    unsigned short* wlbf = (unsigned short*)(ws + 23922752);  // 2048 u16 -> 23923776
    unsigned short* Tinv = (unsigned short*)(ws + 23923776);  // 2048 u16 -> 23924800
    unsigned short* TfT  = (unsigned short*)(ws + 23924800);  // 1024 u16 -> 23925312
    float* Tp1gf = ws + 23925312;              // 1024 f (512 float2)
    float2* Tp1g = (float2*)Tp1gf;

    k_emb<<<2, 256, 0, stream>>>(time_i, conditions, t_embed_w, t_embed_b,
                                 c_embed_w, c_embed_b, lift_b, embk);
    k_wt<<<38, 256, 0, stream>>>(byp_w, lift_w, wbh, wlbf, Tinv, TfT, Tp1gf);
    k_lift<<<8192, 256, 0, stream>>>(state_in, node_pos, wlbf, embk, TfT, xA, a1);

    for (int l = 0; l < 4; l++) {
        unsigned short* xin  = (l & 1) ? xB : xA;
        unsigned short* xout = (l & 1) ? xA : xB;
        const float* wrl = spec_wr + (size_t)l * 524288;
        const float* wil = spec_wi + (size_t)l * 524288;
        k_p1<<<512, 256, 0, stream>>>(a1, Tp1g, a2p);
        k_p2<<<256, 256, 0, stream>>>(a2p, xft);
        k_p3<<<512, 256, 0, stream>>>(xft, wrl, wil, yftp);
        k_p4<<<256, 256, 0, stream>>>(yftp, b1);
        k_fin<<<8192, 256, 0, stream>>>(xin, b1, wbh + l * 1024, byp_b + l * 32,
                                        Tinv, TfT, Tp1g, xout, a1, (l < 3) ? 1 : 0,
                                        (l == 3) ? 1 : 0, state_in,
                                        proj1_w, proj1_b, proj2_w, proj2_b, out);
    }
}

// Round 17
// 344.451 us; speedup vs baseline: 1.1527x; 1.0013x over previous
//
#include <hip/hip_runtime.h>
#include <math.h>

#define PI_F 3.14159265358979323846f

typedef __bf16 bf16x8 __attribute__((ext_vector_type(8)));
typedef float floatx4 __attribute__((ext_vector_type(4)));
union U8 { unsigned short u[8]; uint4 q; bf16x8 v; };

// sigmoid-form GELU: v * sigmoid(1.702 v)
__device__ __forceinline__ float gelu_sig(float v) {
    float e = __builtin_amdgcn_exp2f(-2.4554670f * v);   // exp(-1.702 v)
    return v * __builtin_amdgcn_rcpf(1.0f + e);
}
__device__ __forceinline__ int rfl(int x) { return __builtin_amdgcn_readfirstlane(x); }

__device__ __forceinline__ unsigned short f2bf(float f) {   // RNE fp32->bf16
    unsigned int u = __float_as_uint(f);
    u += 0x7fffu + ((u >> 16) & 1u);
    return (unsigned short)(u >> 16);
}
__device__ __forceinline__ float bf2f(unsigned short h) {
    return __uint_as_float(((unsigned int)h) << 16);
}
__device__ __forceinline__ unsigned int pack2(float a, float b) {
    return (unsigned int)f2bf(a) | ((unsigned int)f2bf(b) << 16);
}

// -------- k_wt: k_emb (blocks 0-1) + bf16 constants + twiddle tables (blocks 2+) --------
__global__ void k_wt(const float* __restrict__ time_i, const float* __restrict__ conditions,
                     const float* __restrict__ t_embed_w, const float* __restrict__ t_embed_b,
                     const float* __restrict__ c_embed_w, const float* __restrict__ c_embed_b,
                     const float* __restrict__ lift_b, float* __restrict__ embk,
                     const float* __restrict__ byp_w, const float* __restrict__ lift_w,
                     unsigned short* __restrict__ wbh, unsigned short* __restrict__ wlbf,
                     unsigned short* __restrict__ Tinv, unsigned short* __restrict__ TfT,
                     float* __restrict__ Tp1g) {
    const float th = PI_F / 32.0f;
    int t = threadIdx.x;
    if (blockIdx.x < 2) {   // embedding
        __shared__ float red[8][32];
        int b = blockIdx.x;
        int c = t & 31, lg = t >> 5;
        float acc = 0.0f;
        if (lg == 0) {
            acc = t_embed_b[c] + c_embed_b[c] + lift_b[c];
            float tv = time_i[b];
            float ang = PI_F * tv;
            const float* tw = t_embed_w + c * 11;
            for (int i = 0; i < 5; i++) {
                float s, co; sincosf(ang, &s, &co);
                acc += co * tw[i] + s * tw[5 + i];
                ang *= 2.0f;
            }
            acc += tv * tw[10];
        }
        const float* cw = c_embed_w + c * 352;
        for (int j = 0; j < 4; j++) {
            int l = lg * 4 + j;
            float v = conditions[b * 32 + l];
            float ang = PI_F * v;
            for (int i = 0; i < 5; i++) {
                float s, co; sincosf(ang, &s, &co);
                acc += co * cw[l * 10 + i] + s * cw[l * 10 + 5 + i];
                ang *= 2.0f;
            }
            acc += v * cw[320 + l];
        }
        red[lg][c] = acc;
        __syncthreads();
        if (t < 32) {
            float s = 0.0f;
            for (int g = 0; g < 8; g++) s += red[g][t];
            embk[b * 32 + t] = s;
        }
        return;
    }
    int idx = (blockIdx.x - 2) * 256 + t;
    if (idx < 4096) {
        wbh[idx] = f2bf(byp_w[idx]);          // [l][o][i] (A-fragment layout)
    } else if (idx < 6144) {
        int j = idx - 4096;                   // o*64 + q
        int o = j >> 6, q = j & 63;
        wlbf[j] = (q < 37) ? f2bf(lift_w[o * 37 + q]) : 0;
    } else if (idx < 8192) {
        int j = idx - 6144;                   // nz*32 + k
        int nz = j >> 5, k = j & 31;
        int kz = k >> 1;
        float val = 0.0f;
        if (kz < 8) {
            float a = (float)((kz * nz) & 63) * th;
            val = (k & 1) ? sinf(a) : cosf(a);
            val *= (kz == 0) ? (1.0f / 262144.0f) : (2.0f / 262144.0f);   // fold scale
        }
        Tinv[j] = f2bf(val);
    } else if (idx < 9216) {
        int j = idx - 8192;                   // kcol*64 + nz
        int kcol = j >> 6, nz = j & 63;
        int kz = kcol >> 1;
        float a = (float)((kz * nz) & 63) * th;
        float val = (kcol & 1) ? -sinf(a) : cosf(a);
        TfT[j] = f2bf(val);
    } else if (idx < 9728) {
        int j = idx - 9216;                   // ny*8 + ky
        int ny = j >> 3, ky = j & 7;
        float a = (float)((ky * ny) & 63) * th;
        Tp1g[j * 2] = cosf(a);
        Tp1g[j * 2 + 1] = sinf(a);
    }
}

// XCD swizzle for 8192-block grids
__device__ __forceinline__ void swz8k(int blk, int& b, int& nx, int& ny) {
    int x = blk & 7;
    int j = blk >> 3;
    int pair = x * 16 + (j >> 6);
    ny = j & 63;
    b = pair >> 6;
    nx = pair & 63;
}

// ------- k_lift: MFMA lift conv + emb + MFMA forward z-DFT. x0, a1 in bf16. -------
__global__ __launch_bounds__(256) void k_lift(const float* __restrict__ state_in,
        const float* __restrict__ node_pos, const unsigned short* __restrict__ wlbf,
        const float* __restrict__ embk, const unsigned short* __restrict__ TfT,
        unsigned short* __restrict__ x0, unsigned int* __restrict__ a1) {
    __shared__ __align__(16) float SL[5024];
    unsigned short* fsT  = (unsigned short*)SL;          // [nz][72] u16 (2304 f)
    unsigned short* ysbf = (unsigned short*)(SL + 2304); // [o][72] u16 (1152 f)
    float* pz   = SL + 3456;                             // 1024 f (compact)
    float* pz2  = SL + 4480;                             // 512 f (linear)
    float* bias = SL + 4992;                             // 32
    int t = threadIdx.x;
    int b, nx, ny; swz8k(blockIdx.x, b, nx, ny);
    int nxy = nx * 64 + ny;

    if (t < 32) bias[t] = embk[b * 32 + t];
    {
        for (int u = t; u < 2048; u += 256) {
            int row = u >> 5, col = 37 + (u & 31);
            fsT[row * 72 + col] = 0;
        }
    }
    if (t < 192) {
        int nzf = t / 3;
        int l = t - nzf * 3;
        float p = node_pos[((size_t)b * 262144 + (nxy << 6)) * 3 + t];
        float s, c; sincosf(PI_F * p, &s, &c);
        unsigned short* row = fsT + nzf * 72;
        #pragma unroll
        for (int i = 0; i < 5; i++) {
            row[4 + l * 10 + i] = f2bf(c);
            row[4 + l * 10 + 5 + i] = f2bf(s);
            float nc = 2.0f * c * c - 1.0f;
            s = 2.0f * s * c;
            c = nc;
        }
        row[34 + l] = f2bf(p);
    } else {
        int nzf = t - 192;
        const float4 s4 = *(const float4*)(state_in + ((size_t)b * 262144 + (nxy << 6) + nzf) * 4);
        unsigned short* row = fsT + nzf * 72;
        row[0] = f2bf(s4.x); row[1] = f2bf(s4.y);
        row[2] = f2bf(s4.z); row[3] = f2bf(s4.w);
    }
    __syncthreads();

    int lane = t & 63;
    int w = rfl(t >> 6);
    int otile = w & 1;
    int nzt0 = (w >> 1) * 2;
    int l15 = lane & 15;
    int quad = lane >> 4;

    U8 a0, a1_;
    a0.q = *(const uint4*)(wlbf + ((otile * 16 + l15) << 6) + (quad << 3));
    a1_.q = *(const uint4*)(wlbf + ((otile * 16 + l15) << 6) + 32 + (quad << 3));
    floatx4 cb;
    #pragma unroll
    for (int r = 0; r < 4; r++) cb[r] = bias[otile * 16 + quad * 4 + r];
    floatx4 dz = {0.0f, 0.0f, 0.0f, 0.0f};

    #pragma unroll
    for (int m = 0; m < 2; m++) {
        int nzc = (nzt0 + m) * 16 + l15;
        U8 b0, b1_;
        b0.q = *(const uint4*)(fsT + nzc * 72 + (quad << 3));
        b1_.q = *(const uint4*)(fsT + nzc * 72 + 32 + (quad << 3));
        floatx4 d = __builtin_amdgcn_mfma_f32_16x16x32_bf16(a0.v, b0.v, cb, 0, 0, 0);
        d = __builtin_amdgcn_mfma_f32_16x16x32_bf16(a1_.v, b1_.v, d, 0, 0, 0);
        #pragma unroll
        for (int r = 0; r < 4; r++) {
            int o = otile * 16 + quad * 4 + r;
            ysbf[o * 72 + nzc] = f2bf(d[r]);
        }
    }
    __syncthreads();
    {   // coalesced x0 write
        int ch = t >> 3, q = t & 7;
        uint4 v = *(const uint4*)(ysbf + ch * 72 + q * 8);
        *(uint4*)(x0 + (((size_t)(b * 32 + ch)) << 18) + (nxy << 6) + q * 8) = v;
    }
    {   // forward z-DFT via MFMA: wave (otile, khalf)
        int khalf = w >> 1;
        U8 ay, bt;
        ay.q = *(const uint4*)(ysbf + (otile * 16 + l15) * 72 + khalf * 32 + (quad << 3));
        bt.q = *(const uint4*)(TfT + (l15 << 6) + khalf * 32 + (quad << 3));
        floatx4 d = __builtin_amdgcn_mfma_f32_16x16x32_bf16(ay.v, bt.v, dz, 0, 0, 0);
        *(floatx4*)(pz + w * 256 + lane * 4) = d;
    }
    __syncthreads();
    if (w < 2) {
        float4 p0 = *(float4*)(pz + w * 256 + lane * 4);
        float4 p1 = *(float4*)(pz + (w + 2) * 256 + lane * 4);
        float pv[4] = {p0.x + p1.x, p0.y + p1.y, p0.z + p1.z, p0.w + p1.w};
        #pragma unroll
        for (int r = 0; r < 4; r++)
            pz2[(otile * 16 + quad * 4 + r) * 16 + l15] = pv[r];
    }
    __syncthreads();
    if (t < 128) {   // pack 4 floats (2 complex) -> 2 uints, coalesced 1 KB
        float4 v = *(float4*)(pz2 + t * 4);
        unsigned int* a1p = a1 + ((size_t)(b * 4096 + nxy)) * 256;
        *(uint2*)(a1p + t * 2) = make_uint2(pack2(v.x, v.y), pack2(v.z, v.w));
    }
}

// =================== spectral mid-section ===================

// k_p1: forward y-DFT over ny-QUARTERS, bf16-packed a1 input. 512 blocks.
__global__ __launch_bounds__(256) void k_p1(const unsigned int* __restrict__ a1,
        const float2* __restrict__ Tp1g, float2* __restrict__ a2p) {
    int blk = blockIdx.x, t = threadIdx.x;
    int x = blk & 7, r = blk >> 3;        // r 0..63
    int pair = x * 16 + (r & 15);
    int qtr = r >> 4;                     // 0..3
    const unsigned int* src = a1 + ((size_t)(pair * 64 + qtr * 16)) * 256 + t;
    float accr[8], acci[8];
    #pragma unroll
    for (int k = 0; k < 8; k++) { accr[k] = 0.0f; acci[k] = 0.0f; }
    #pragma unroll 4
    for (int j = 0; j < 16; j++) {
        int ny = qtr * 16 + j;
        unsigned int pv = src[(size_t)j * 256];
        float vx = bf2f((unsigned short)(pv & 0xffffu));
        float vy = bf2f((unsigned short)(pv >> 16));
        const float2* tw = Tp1g + ny * 8;    // block-uniform -> s_load
        #pragma unroll
        for (int ky = 0; ky < 8; ky++) {
            float2 w2 = tw[ky];
            accr[ky] += vx * w2.x + vy * w2.y;   // e^{-i ky ny θ}
            acci[ky] += vy * w2.x - vx * w2.y;
        }
    }
    float4* dst = (float4*)(a2p + (size_t)qtr * 262144 + ((size_t)(pair * 256 + t)) * 8);
    #pragma unroll
    for (int j = 0; j < 4; j++)
        dst[j] = make_float4(accr[2 * j], acci[2 * j], accr[2 * j + 1], acci[2 * j + 1]);
}

// k_p2: forward x-DFT (sums 4 quarter-partials)
__global__ __launch_bounds__(256) void k_p2(const float2* __restrict__ a2p,
                                            float2* __restrict__ xft) {
    __shared__ __align__(16) float2 SH[1040];
    int blk = blockIdx.x, t = threadIdx.x;
    for (int lu = 0; lu < 2; lu++) {
        int un = blk * 2 + lu;
        int b = un >> 8, ckz = un & 255;
        size_t base = (size_t)b * 131072 + (size_t)ckz * 8;
        for (int e = t; e < 512; e += 256) {
            size_t a = base + (size_t)(e >> 3) * 2048 + (e & 7);
            float2 v0 = a2p[a];
            float2 v1 = a2p[a + 262144];
            float2 v2 = a2p[a + 524288];
            float2 v3 = a2p[a + 786432];
            SH[lu * 520 + e] = make_float2(v0.x + v1.x + v2.x + v3.x,
                                           v0.y + v1.y + v2.y + v3.y);
        }
    }
    __syncthreads();
    if (t < 128) {
        int lu = t >> 6, out = t & 63;
        int un = blk * 2 + lu;
        int kx = out & 7;
        float sn, cc; sincosf((float)kx * (PI_F / 32.0f), &sn, &cc);
        float bsn = -sn;
        float tc = 1.0f, ts = 0.0f, rr = 0.0f, ri = 0.0f;
        const float2* row = SH + lu * 520 + (out >> 3);
        for (int nx = 0; nx < 64; nx++) {
            float2 v = row[nx * 8];
            rr += v.x * tc - v.y * ts;
            ri += v.x * ts + v.y * tc;
            float nt = tc * cc - ts * bsn; ts = ts * cc + tc * bsn; tc = nt;
        }
        xft[(size_t)un * 64 + out] = make_float2(rr, ri);
    }
}

// k_p3: mode mix over i-QUARTERS. 512 blocks.
__global__ __launch_bounds__(256) void k_p3(const float2* __restrict__ xft,
        const float* __restrict__ wr, const float* __restrict__ wi,
        float2* __restrict__ yftp) {
    __shared__ __align__(16) float2 SH[64];
    int blk = blockIdx.x, t = threadIdx.x;
    int unit = blk >> 2, iq = blk & 3;
    int b = unit >> 6, kx = (unit >> 3) & 7, ky = unit & 7;
    if (t < 64) {
        int il = t >> 3, kz = t & 7;
        int i = iq * 8 + il;
        SH[t] = xft[((size_t)((b * 32 + i) * 8 + kz)) * 64 + ky * 8 + kx];
    }
    __syncthreads();
    int o = t >> 3, kz = t & 7;
    float yr = 0.0f, yi = 0.0f;
    for (int il = 0; il < 8; il++) {
        int i = iq * 8 + il;
        float2 xv = SH[il * 8 + kz];
        int wofs = ((i * 32 + o) << 9) + kx * 64 + ky * 8 + kz;
        float wrv = wr[wofs], wiv = wi[wofs];
        yr += xv.x * wrv - xv.y * wiv;
        yi += xv.x * wiv + xv.y * wrv;
    }
    yftp[(size_t)iq * 32768 + ((size_t)((b * 32 + o) * 8 + kz)) * 64 + ky * 8 + kx]
        = make_float2(yr, yi);
}

// k_p4: inverse x (sums 4 quarter-partials) -> b1[b][nx][o*8+kz][ky]
__global__ __launch_bounds__(256) void k_p4(const float2* __restrict__ yftp,
                                            float2* __restrict__ b1) {
    __shared__ __align__(16) float2 SH[4608];
    int blk = blockIdx.x, t = threadIdx.x;
    for (int u = 0; u < 2; u++) {
        if (u) __syncthreads();
        int unit = blk * 2 + u;
        int b = unit >> 8, nx = (unit >> 2) & 63, og = unit & 3;
        size_t sbase = ((size_t)(b * 32 + og * 8)) * 512;
        for (int e = t; e < 4096; e += 256) {
            float2 v0 = yftp[sbase + e];
            float2 v1 = yftp[32768 + sbase + e];
            float2 v2 = yftp[65536 + sbase + e];
            float2 v3 = yftp[98304 + sbase + e];
            SH[(e >> 3) * 9 + (e & 7)] = make_float2(v0.x + v1.x + v2.x + v3.x,
                                                     v0.y + v1.y + v2.y + v3.y);
        }
        __syncthreads();
        float cs, ss; sincosf((float)nx * (PI_F / 32.0f), &ss, &cs);
        float2* dst = b1 + ((size_t)(b * 64 + nx)) * 2048 + og * 512;
        for (int h = 0; h < 2; h++) {
            int idx = h * 256 + t;
            const float2* row = SH + idx * 9;
            float c = 1.0f, s = 0.0f, rr = 0.0f, ri = 0.0f;
            #pragma unroll
            for (int kx = 0; kx < 8; kx++) {
                float2 y = row[kx];
                rr += y.x * c - y.y * s;
                ri += y.x * s + y.y * c;
                float nc = c * cs - s * ss; s = s * cs + c * ss; c = nc;
            }
            dst[idx] = make_float2(rr, ri);
        }
    }
}

// ------- k_fin: register inverse-y (direct global b1 read, s_load twiddles)
//         + chained MFMA (bypass + inverse-z) + gelu
//         + (l<3) MFMA fwd z-DFT (bf16 a1)  OR  (l==3) fused proj+residual -------
__global__ __launch_bounds__(256) void k_fin(
        const unsigned short* __restrict__ xin, const float2* __restrict__ b1,
        const unsigned short* __restrict__ wbh, const float* __restrict__ bb,
        const unsigned short* __restrict__ Tinv, const unsigned short* __restrict__ TfT,
        const float2* __restrict__ Tp1g, unsigned short* __restrict__ xout,
        unsigned int* __restrict__ a1, int do_z, int do_proj,
        const float* __restrict__ state_in, const float* __restrict__ p1w,
        const float* __restrict__ p1b, const float* __restrict__ p2w,
        const float* __restrict__ p2b, float* __restrict__ outp) {
    __shared__ __align__(16) float S[4416];
    float* pz   = S;                              // 1024 (fwd-z compact partials)
    float* pz2  = S + 1024;                       // 512 (linear)
    float* pr   = S;                              // 1024 alias (proj partials)
    unsigned short* xsu  = (unsigned short*)(S + 1536);  // [ch][66] u16 (1056 f)
    unsigned short* msbf = (unsigned short*)(S + 2592);  // [o][40] u16 (640 f)
    unsigned short* ysbf = (unsigned short*)(S + 3232);  // [o][72] u16 (1152 f)
    float* bias = S + 4384;                       // 32
    int t = threadIdx.x;
    int b, nx, ny; swz8k(blockIdx.x, b, nx, ny);
    int nxy = nx * 64 + ny;

    if (t >= 96 && t < 128) bias[t - 96] = bb[t - 96];
    ((unsigned int*)msbf)[(t >> 3) * 20 + 8 + (t & 7)] = 0;   // zero K-pad cols 16..31
    {   // stage x (bf16): one uint4 (8 elems) per thread -> xsu pitch 66
        int ch = t >> 3, q = t & 7;
        uint4 v = *(const uint4*)(xin + (((size_t)b) << 23) + (nxy << 6)
                                  + ((size_t)ch << 18) + q * 8);
        unsigned int* dst = (unsigned int*)(xsu + ch * 66 + q * 8);
        dst[0] = v.x; dst[1] = v.y; dst[2] = v.z; dst[3] = v.w;
    }
    {   // inverse-y fully in registers: thread t reads its contiguous 64 B b1 row
        const float4* g = (const float4*)(b1 + ((size_t)(b * 64 + nx)) * 2048
                                          + (size_t)t * 8);
        float4 g0 = g[0], g1 = g[1], g2 = g[2], g3 = g[3];
        float vr[8], vi[8];
        vr[0] = g0.x; vi[0] = g0.y; vr[1] = g0.z; vi[1] = g0.w;
        vr[2] = g1.x; vi[2] = g1.y; vr[3] = g1.z; vi[3] = g1.w;
        vr[4] = g2.x; vi[4] = g2.y; vr[5] = g2.z; vi[5] = g2.w;
        vr[6] = g3.x; vi[6] = g3.y; vr[7] = g3.z; vi[7] = g3.w;
        const float2* tw = Tp1g + ny * 8;          // block-uniform -> s_load
        float mr = 0.0f, mi = 0.0f;
        #pragma unroll
        for (int ky = 0; ky < 8; ky++) {
            float2 w2 = tw[ky];
            mr += vr[ky] * w2.x - vi[ky] * w2.y;   // e^{+i ky ny θ}
            mi += vr[ky] * w2.y + vi[ky] * w2.x;
        }
        ((unsigned int*)msbf)[(t >> 3) * 20 + (t & 7)] = pack2(mr, -mi);
    }
    __syncthreads();

    // ---- chained MFMA: D = bias + W·X (bypass) + M2·Tinv (inverse-z, scale in Tinv) ----
    int lane = t & 63;
    int w = rfl(t >> 6);
    int otile = w & 1;
    int nzt0 = (w >> 1) * 2;
    int l15 = lane & 15;
    int quad = lane >> 4;

    U8 aw, ams;
    aw.q = *(const uint4*)(wbh + ((otile * 16 + l15) << 5) + (quad << 3));
    ams.q = *(const uint4*)(msbf + (otile * 16 + l15) * 40 + (quad << 3));
    floatx4 cb;
    #pragma unroll
    for (int r = 0; r < 4; r++) cb[r] = bias[otile * 16 + quad * 4 + r];
    floatx4 dzero = {0.0f, 0.0f, 0.0f, 0.0f};

    size_t colbase = (((size_t)b) << 23) + (nxy << 6);

    #pragma unroll
    for (int m = 0; m < 2; m++) {
        int nzc = (nzt0 + m) * 16 + l15;
        U8 bx, bt;
        #pragma unroll
        for (int j = 0; j < 8; j++) bx.u[j] = xsu[(quad * 8 + j) * 66 + nzc];
        bt.q = *(const uint4*)(Tinv + (nzc << 5) + (quad << 3));   // global, L1-broadcast
        floatx4 d = __builtin_amdgcn_mfma_f32_16x16x32_bf16(aw.v, bx.v, cb, 0, 0, 0);
        d = __builtin_amdgcn_mfma_f32_16x16x32_bf16(ams.v, bt.v, d, 0, 0, 0);
        #pragma unroll
        for (int r = 0; r < 4; r++) {
            int o = otile * 16 + quad * 4 + r;
            ysbf[o * 72 + nzc] = f2bf(gelu_sig(d[r]));
        }
    }
    __syncthreads();

    if (!do_proj) {   // coalesced xout write: one uint4 (8 bf16) per thread
        int ch = t >> 3, q = t & 7;
        uint4 v = *(const uint4*)(ysbf + ch * 72 + q * 8);
        *(uint4*)(xout + colbase + ((size_t)ch << 18) + q * 8) = v;
    }

    if (do_z) {
        int khalf = w >> 1;
        U8 ay, bt;
        ay.q = *(const uint4*)(ysbf + (otile * 16 + l15) * 72 + khalf * 32 + (quad << 3));
        bt.q = *(const uint4*)(TfT + (l15 << 6) + khalf * 32 + (quad << 3));
        floatx4 d = __builtin_amdgcn_mfma_f32_16x16x32_bf16(ay.v, bt.v, dzero, 0, 0, 0);
        *(floatx4*)(pz + w * 256 + lane * 4) = d;
        __syncthreads();
        if (w < 2) {
            float4 p0 = *(float4*)(pz + w * 256 + lane * 4);
            float4 p1 = *(float4*)(pz + (w + 2) * 256 + lane * 4);
            float pv[4] = {p0.x + p1.x, p0.y + p1.y, p0.z + p1.z, p0.w + p1.w};
            #pragma unroll
            for (int r = 0; r < 4; r++)
                pz2[(otile * 16 + quad * 4 + r) * 16 + l15] = pv[r];
        }
        __syncthreads();
        if (t < 128) {   // pack 4 floats (2 complex) -> 2 uints, coalesced 1 KB
            float4 v = *(float4*)(pz2 + t * 4);
            unsigned int* a1p = a1 + ((size_t)(b * 4096 + nxy)) * 256;
            *(uint2*)(a1p + t * 2) = make_uint2(pack2(v.x, v.y), pack2(v.z, v.w));
        }
    }

    if (do_proj) {                  // fused proj1 -> gelu -> proj2 -> residual
        int nz = t & 63;
        float xv[32];
        #pragma unroll
        for (int i = 0; i < 32; i++) xv[i] = bf2f(ysbf[i * 72 + nz]);
        float r0 = 0.f, r1 = 0.f, r2 = 0.f, r3 = 0.f;
        #pragma unroll
        for (int k = 0; k < 8; k++) {
            int o = w * 8 + k;
            float a = p1b[o];                                   // s_load
            const float* wr = p1w + o * 32;                     // s_load
            #pragma unroll
            for (int i = 0; i < 32; i++) a += wr[i] * xv[i];
            float h = gelu_sig(a);
            r0 += p2w[0 * 32 + o] * h;
            r1 += p2w[1 * 32 + o] * h;
            r2 += p2w[2 * 32 + o] * h;
            r3 += p2w[3 * 32 + o] * h;
        }
        *(float4*)(pr + w * 256 + nz * 4) = make_float4(r0, r1, r2, r3);
        __syncthreads();
        if (t < 64) {
            float4 a0 = *(float4*)(pr + 0 * 256 + t * 4);
            float4 a1_ = *(float4*)(pr + 1 * 256 + t * 4);
            float4 a2 = *(float4*)(pr + 2 * 256 + t * 4);
            float4 a3 = *(float4*)(pr + 3 * 256 + t * 4);
            size_t base = ((size_t)b * 262144 + (nxy << 6) + t) * 4;
            float4 sv = *(const float4*)(state_in + base);
            *(float4*)(outp + base) = make_float4(
                sv.x + 0.05f * (p2b[0] + a0.x + a1_.x + a2.x + a3.x),
                sv.y + 0.05f * (p2b[1] + a0.y + a1_.y + a2.y + a3.y),
                sv.z + 0.05f * (p2b[2] + a0.z + a1_.z + a2.z + a3.z),
                sv.w + 0.05f * (p2b[3] + a0.w + a1_.w + a2.w + a3.w));
        }
    }
}

extern "C" void kernel_launch(void* const* d_in, const int* in_sizes, int n_in,
                              void* d_out, int out_size, void* d_ws, size_t ws_size,
                              hipStream_t stream) {
    const float* state_in   = (const float*)d_in[0];
    const float* node_pos   = (const float*)d_in[1];
    const float* time_i     = (const float*)d_in[3];
    const float* conditions = (const float*)d_in[4];
    const float* t_embed_w  = (const float*)d_in[5];
    const float* t_embed_b  = (const float*)d_in[6];
    const float* c_embed_w  = (const float*)d_in[7];
    const float* c_embed_b  = (const float*)d_in[8];
    const float* lift_w     = (const float*)d_in[9];
    const float* lift_b     = (const float*)d_in[10];
    const float* spec_wr    = (const float*)d_in[11];
    const float* spec_wi    = (const float*)d_in[12];
    const float* byp_w      = (const float*)d_in[13];
    const float* byp_b      = (const float*)d_in[14];
    const float* proj1_w    = (const float*)d_in[15];
    const float* proj1_b    = (const float*)d_in[16];
    const float* proj2_w    = (const float*)d_in[17];
    const float* proj2_b    = (const float*)d_in[18];
    float* out = (float*)d_out;
    float* ws  = (float*)d_ws;

    unsigned short* xA = (unsigned short*)ws;                 // 16777216 u16
    unsigned short* xB = (unsigned short*)(ws + 8388608);     // 16777216 u16
    unsigned int* a1 = (unsigned int*)(ws + 16777216);        // 1048576 uint (bf16x2)
    float2* a2p  = (float2*)(ws + 20971520);   // 1048576 f2 -> 23068672
    float2* xft  = (float2*)(ws + 23068672);   // 32768 f2   -> 23134208
    float2* yftp = (float2*)(ws + 23134208);   // 131072 f2  -> 23396352
    float2* b1   = (float2*)(ws + 23396352);   // 262144 f2  -> 23920640
    float*  embk = ws + 23920640;              // 64
    unsigned short* wbh  = (unsigned short*)(ws + 23920704);  // 4096 u16 -> 23922752
    unsigned short* wlbf = (unsigned short*)(ws + 23922752);  // 2048 u16 -> 23923776
    unsigned short* Tinv = (unsigned short*)(ws + 23923776);  // 2048 u16 -> 23924800
    unsigned short* TfT  = (unsigned short*)(ws + 23924800);  // 1024 u16 -> 23925312
    float* Tp1gf = ws + 23925312;              // 1024 f (512 float2)
    float2* Tp1g = (float2*)Tp1gf;

    k_wt<<<40, 256, 0, stream>>>(time_i, conditions, t_embed_w, t_embed_b,
                                 c_embed_w, c_embed_b, lift_b, embk,
                                 byp_w, lift_w, wbh, wlbf, Tinv, TfT, Tp1gf);
    k_lift<<<8192, 256, 0, stream>>>(state_in, node_pos, wlbf, embk, TfT, xA, a1);

    for (int l = 0; l < 4; l++) {
        unsigned short* xin  = (l & 1) ? xB : xA;
        unsigned short* xout = (l & 1) ? xA : xB;
        const float* wrl = spec_wr + (size_t)l * 524288;
        const float* wil = spec_wi + (size_t)l * 524288;
        k_p1<<<512, 256, 0, stream>>>(a1, Tp1g, a2p);
        k_p2<<<256, 256, 0, stream>>>(a2p, xft);
        k_p3<<<512, 256, 0, stream>>>(xft, wrl, wil, yftp);
        k_p4<<<256, 256, 0, stream>>>(yftp, b1);
        k_fin<<<8192, 256, 0, stream>>>(xin, b1, wbh + l * 1024, byp_b + l * 32,
                                        Tinv, TfT, Tp1g, xout, a1, (l < 3) ? 1 : 0,
                                        (l == 3) ? 1 : 0, state_in,
                                        proj1_w, proj1_b, proj2_w, proj2_b, out);
    }
}